// Round 2
// 766.764 us; speedup vs baseline: 3.0348x; 3.0348x over previous
//
#include <hip/hip_runtime.h>

typedef unsigned short u16;
typedef unsigned int   u32;
typedef __attribute__((ext_vector_type(8))) short bf16x8;
typedef __attribute__((ext_vector_type(4))) float f32x4;

#define L_TOK   16384
#define C_DIM   192
#define HID_DIM 768

union FragU { int4 i4; bf16x8 h8; };

#define MFMA_B16(a,b,c) __builtin_amdgcn_mfma_f32_16x16x32_bf16(a,b,c,0,0,0)

__device__ __forceinline__ u16 f2bf(float f) {
    u32 t; __builtin_memcpy(&t, &f, 4);
    t += 0x7FFFu + ((t >> 16) & 1u);
    return (u16)(t >> 16);
}

// ---------------------------------------------------------------------------
// Kernel 1: per-window fused LN1 + MFMA qkv + MFMA scores + softmax + MFMA P@V
// + MFMA proj + residual -> x1 (f32, token order, in d_out).
// grid 2048, block 256 (4 waves; wave w owns query rows w*16..+15).
// LDS ~49.9 KB -> 3 blocks/CU (12 waves/CU).
// All attention matmuls on the matrix pipe; VALU only does LN, staging
// f2bf packs, bias/mask/softmax, and the epilogue.
// ---------------------------------------------------------------------------
__global__ __launch_bounds__(256) void k_attnproj(
    const float* __restrict__ x, const float* __restrict__ g1v, const float* __restrict__ b1v,
    const float* __restrict__ qkvw, const float* __restrict__ qkvb,
    const float* __restrict__ relb, const float* __restrict__ projw, const float* __restrict__ projb,
    float* __restrict__ x1)
{
    // xw (LN'd tokens) is only needed until the A-fragments are preloaded into
    // registers; afterwards its LDS is reused for the per-head q/k/v/P/O tiles.
    union SmemU {
        u16 xw[64 * 192];                       // 24576 B (phase A only)
        struct {
            u16 qsb[64 * 40];                   //  5120 B  Q rows  [tok][dim]
            u16 ksb[64 * 40];                   //  5120 B  K rows  [tok][dim]
            u16 vsbT[32 * 72];                  //  4608 B  V^T     [dim][tok]
            u16 psb[64 * 72];                   //  9216 B  P       [tok][key]
            u16 oh [64 * 40];                   //  5120 B  O       [tok][dim]
        } s;                                    // 29184 B total
    };
    __shared__ __align__(16) SmemU u;
    __shared__ __align__(16) u16 wbuf[192 * 40];   // 15360 B: wTh[96][72] / wP[192][40]
    __shared__ float relbs[225 * 6];               //  5400 B: staged rel-pos bias

    const int wi = blockIdx.x;
    const int b  = wi >> 8;
    const int hb = (wi >> 4) & 15;
    const int wb = wi & 15;
    const int t  = threadIdx.x;
    const int lane = t & 63, w = t >> 6;
    const int l15 = lane & 15, quad = lane >> 4;
    const bool maskon = (hb == 15) || (wb == 15);
    const f32x4 zf = {0.f, 0.f, 0.f, 0.f};

    // stage rel-pos bias table to LDS (read 16x per lane per head later)
    for (int i = t; i < 225 * 6; i += 256) relbs[i] = relb[i];

    // ---- Phase A: load + LayerNorm1, stage to LDS as bf16 ----
    {
        const int n  = t >> 2;        // token in window
        const int q4 = t & 3;         // quartet lane
        const int r = n >> 3, c = n & 7;
        const int ho = (hb * 8 + r + 4) & 127;    // undo roll(-4,-4)
        const int wo = (wb * 8 + c + 4) & 127;
        const size_t xoff = ((size_t)b * L_TOK + ho * 128 + wo) * C_DIM;
        const float* xp = x + xoff + q4 * 48;
        float f[48];
        float sum = 0.f, sq = 0.f;
        #pragma unroll
        for (int i = 0; i < 12; ++i) {
            float4 v = *(const float4*)(xp + i * 4);
            f[i*4+0]=v.x; f[i*4+1]=v.y; f[i*4+2]=v.z; f[i*4+3]=v.w;
            sum += v.x+v.y+v.z+v.w;
            sq  += v.x*v.x + v.y*v.y + v.z*v.z + v.w*v.w;
        }
        sum += __shfl_xor(sum, 1); sum += __shfl_xor(sum, 2);
        sq  += __shfl_xor(sq, 1);  sq  += __shfl_xor(sq, 2);
        const float mu = sum * (1.f / 192.f);
        const float rstd = rsqrtf(sq * (1.f / 192.f) - mu * mu + 1e-5f);
        u16* xrow = u.xw + n * 192 + q4 * 48;
        #pragma unroll
        for (int i = 0; i < 6; ++i) {
            u32 pk[4];
            #pragma unroll
            for (int j = 0; j < 4; ++j) {
                float g0 = g1v[q4*48 + i*8 + j*2],     b0 = b1v[q4*48 + i*8 + j*2];
                float g1 = g1v[q4*48 + i*8 + j*2 + 1], b1 = b1v[q4*48 + i*8 + j*2 + 1];
                float y0 = (f[i*8+j*2]   - mu) * rstd * g0 + b0;
                float y1 = (f[i*8+j*2+1] - mu) * rstd * g1 + b1;
                pk[j] = (u32)f2bf(y0) | (((u32)f2bf(y1)) << 16);
            }
            *(int4*)(xrow + i * 8) = make_int4((int)pk[0], (int)pk[1], (int)pk[2], (int)pk[3]);
        }
    }
    __syncthreads();

    // preload A-fragments (this wave's 16 query rows x full C), reused all heads
    FragU afrag[6];
    #pragma unroll
    for (int kk = 0; kk < 6; ++kk)
        afrag[kk].i4 = *(const int4*)(u.xw + (w*16 + l15) * 192 + kk*32 + quad*8);
    // NOTE: xw is dead from here on (aliased by q/k/v/P/O tiles). The first
    // write into the alias happens after the kc-loop barriers below, by which
    // point every wave's afrag reads have completed (barrier drains lgkm).

    const int qrow0 = w*16 + quad*4;   // first of this lane's 4 accumulator rows

    f32x4 acc2[12];
    #pragma unroll
    for (int nt = 0; nt < 12; ++nt) acc2[nt] = zf;

    for (int head = 0; head < 6; ++head) {
        // ---- Phase B: qkv via MFMA (N=96: q|k|v 32 each), K chunked by 64 ----
        f32x4 accq[6];
        #pragma unroll
        for (int nt = 0; nt < 6; ++nt) accq[nt] = zf;

        for (int kc = 0; kc < 3; ++kc) {
            __syncthreads();   // protects wbuf reuse (prev head's proj reads / wTh reads)
            if (t < 192) {     // stage W^T chunk: col cc, k-half kh
                const int cc = t % 96, kh = t / 96;
                const int grp = cc >> 5, dim = cc & 31;
                const float* gp = qkvw + (size_t)(kc*64 + kh*32) * 576 + grp*192 + head*32 + dim;
                u16* dst = wbuf + cc*72 + kh*32;
                #pragma unroll
                for (int g = 0; g < 4; ++g) {
                    u32 pk[4];
                    #pragma unroll
                    for (int j2 = 0; j2 < 4; ++j2) {
                        float v0 = gp[(size_t)(g*8 + j2*2    ) * 576];
                        float v1 = gp[(size_t)(g*8 + j2*2 + 1) * 576];
                        pk[j2] = (u32)f2bf(v0) | (((u32)f2bf(v1)) << 16);
                    }
                    *(int4*)(dst + g*8) = make_int4((int)pk[0], (int)pk[1], (int)pk[2], (int)pk[3]);
                }
            }
            __syncthreads();
            #pragma unroll
            for (int s = 0; s < 2; ++s) {
                #pragma unroll
                for (int nt = 0; nt < 6; ++nt) {
                    FragU bf_;
                    bf_.i4 = *(const int4*)(wbuf + (nt*16 + l15)*72 + s*32 + quad*8);
                    accq[nt] = MFMA_B16(afrag[kc*2 + s].h8, bf_.h8, accq[nt]);
                }
            }
        }
        // store q/k row-major, v transposed. D layout: tok=qrow0+rg, col=nt*16+l15
        #pragma unroll
        for (int nt = 0; nt < 6; ++nt) {
            const int grp = nt >> 1;             // 0=q,1=k,2=v (uniform per nt)
            const int dim = (nt & 1)*16 + l15;   // dim within 32-wide head slice
            const float bias = qkvb[grp*192 + head*32 + dim];
            float vv[4];
            #pragma unroll
            for (int rg = 0; rg < 4; ++rg) vv[rg] = accq[nt][rg] + bias;
            if (grp == 0) {
                #pragma unroll
                for (int rg = 0; rg < 4; ++rg)
                    u.s.qsb[(qrow0 + rg)*40 + dim] = f2bf(vv[rg] * 0.17677669529663687f);
            } else if (grp == 1) {
                #pragma unroll
                for (int rg = 0; rg < 4; ++rg)
                    u.s.ksb[(qrow0 + rg)*40 + dim] = f2bf(vv[rg]);
            } else {
                u32 lo = (u32)f2bf(vv[0]) | (((u32)f2bf(vv[1])) << 16);
                u32 hi = (u32)f2bf(vv[2]) | (((u32)f2bf(vv[3])) << 16);
                *(uint2*)&u.s.vsbT[dim*72 + w*16 + quad*4] = make_uint2(lo, hi);
            }
        }
        __syncthreads();   // q/k/vT visible to all waves

        // ---- Phase C: scores via MFMA. B-frag wants [key][dim] = ksb as-is ----
        FragU qf; qf.i4 = *(const int4*)(u.s.qsb + (w*16 + l15)*40 + quad*8);
        f32x4 sv[4];
        #pragma unroll
        for (int nt = 0; nt < 4; ++nt) {
            FragU kf; kf.i4 = *(const int4*)(u.s.ksb + (nt*16 + l15)*40 + quad*8);
            sv[nt] = MFMA_B16(qf.h8, kf.h8, zf);
        }
        // bias (+ shift-window mask, block-uniform branch)
        const int kr_ = l15 >> 3, kc2 = l15 & 7;
        #pragma unroll
        for (int rg = 0; rg < 4; ++rg) {
            const int qm = qrow0 + rg;
            const int qr = qm >> 3, qc = qm & 7;
            #pragma unroll
            for (int nt = 0; nt < 4; ++nt) {
                const int kr = nt*2 + kr_;
                sv[nt][rg] += relbs[((qr - kr + 7)*15 + (qc - kc2 + 7))*6 + head];
            }
        }
        if (maskon) {
            #pragma unroll
            for (int rg = 0; rg < 4; ++rg) {
                const int qm = qrow0 + rg;
                const int qr = qm >> 3, qc = qm & 7;
                const int regq = ((hb == 15) ? (qr < 4 ? 1 : 2) : 0) * 3
                               + ((wb == 15) ? (qc < 4 ? 1 : 2) : 0);
                #pragma unroll
                for (int nt = 0; nt < 4; ++nt) {
                    const int kr = nt*2 + kr_;
                    const int regk = ((hb == 15) ? (kr < 4 ? 1 : 2) : 0) * 3
                                   + ((wb == 15) ? (kc2 < 4 ? 1 : 2) : 0);
                    if (regq != regk) sv[nt][rg] -= 100.f;
                }
            }
        }
        // ---- Phase D: softmax per row (row spread across 16-lane group) ----
        #pragma unroll
        for (int rg = 0; rg < 4; ++rg) {
            float mx = fmaxf(fmaxf(sv[0][rg], sv[1][rg]), fmaxf(sv[2][rg], sv[3][rg]));
            mx = fmaxf(mx, __shfl_xor(mx, 1));
            mx = fmaxf(mx, __shfl_xor(mx, 2));
            mx = fmaxf(mx, __shfl_xor(mx, 4));
            mx = fmaxf(mx, __shfl_xor(mx, 8));
            float s0 = 0.f;
            #pragma unroll
            for (int nt = 0; nt < 4; ++nt) { sv[nt][rg] = __expf(sv[nt][rg] - mx); s0 += sv[nt][rg]; }
            s0 += __shfl_xor(s0, 1); s0 += __shfl_xor(s0, 2);
            s0 += __shfl_xor(s0, 4); s0 += __shfl_xor(s0, 8);
            const float inv = 1.f / s0;
            #pragma unroll
            for (int nt = 0; nt < 4; ++nt)
                u.s.psb[(qrow0 + rg)*72 + nt*16 + l15] = f2bf(sv[nt][rg] * inv);
        }
        // psb rows w*16..+15 are written and read by THIS wave only -> no barrier.

        // ---- Phase E: P@V via MFMA (A=P from psb, B=V^T from vsbT) ----
        FragU pa0, pa1;
        pa0.i4 = *(const int4*)(u.s.psb + (w*16 + l15)*72 + quad*8);
        pa1.i4 = *(const int4*)(u.s.psb + (w*16 + l15)*72 + 32 + quad*8);
        f32x4 ov[2];
        ov[0] = zf; ov[1] = zf;
        #pragma unroll
        for (int ntv = 0; ntv < 2; ++ntv) {
            FragU vb0, vb1;
            vb0.i4 = *(const int4*)(u.s.vsbT + (ntv*16 + l15)*72 + quad*8);
            vb1.i4 = *(const int4*)(u.s.vsbT + (ntv*16 + l15)*72 + 32 + quad*8);
            ov[ntv] = MFMA_B16(pa0.h8, vb0.h8, ov[ntv]);
            ov[ntv] = MFMA_B16(pa1.h8, vb1.h8, ov[ntv]);
        }
        #pragma unroll
        for (int ntv = 0; ntv < 2; ++ntv)
            #pragma unroll
            for (int rg = 0; rg < 4; ++rg)
                u.s.oh[(qrow0 + rg)*40 + ntv*16 + l15] = f2bf(ov[ntv][rg]);
        // oh rows are also wave-private -> no barrier before A-frag read below.

        // ---- Phase P: stage projw^T chunk, proj via MFMA (acc over heads) ----
        if (t < 192) {   // wP[c][j] = projw[head*32+j][c]; coalesced across lanes
            const float* gp = projw + (size_t)(head * 32) * C_DIM + t;
            u16* dst = wbuf + t*40;
            #pragma unroll
            for (int g = 0; g < 4; ++g) {
                u32 pk[4];
                #pragma unroll
                for (int j2 = 0; j2 < 4; ++j2) {
                    float v0 = gp[(size_t)(g*8 + j2*2    ) * C_DIM];
                    float v1 = gp[(size_t)(g*8 + j2*2 + 1) * C_DIM];
                    pk[j2] = (u32)f2bf(v0) | (((u32)f2bf(v1)) << 16);
                }
                *(int4*)(dst + g*8) = make_int4((int)pk[0], (int)pk[1], (int)pk[2], (int)pk[3]);
            }
        }
        __syncthreads();   // wP staged (wTh reads finished before prev barrier)
        FragU ao; ao.i4 = *(const int4*)(u.s.oh + (w*16 + l15)*40 + quad*8);
        #pragma unroll
        for (int nt = 0; nt < 12; ++nt) {
            FragU bp; bp.i4 = *(const int4*)(wbuf + (nt*16 + l15)*40 + quad*8);
            acc2[nt] = MFMA_B16(ao.h8, bp.h8, acc2[nt]);
        }
        // next head's kc-loop barrier protects wbuf before restaging
    }

    // ---- Phase F: + proj bias + residual, write x1 (f32, token order) ----
    {
        float pb[12];
        #pragma unroll
        for (int nt = 0; nt < 12; ++nt) pb[nt] = projb[nt*16 + l15];
        #pragma unroll
        for (int rg = 0; rg < 4; ++rg) {
            const int tok = qrow0 + rg;
            const int tr = tok >> 3, tc = tok & 7;
            const int ho2 = (hb * 8 + tr + 4) & 127;
            const int wo2 = (wb * 8 + tc + 4) & 127;
            const size_t base = ((size_t)b * L_TOK + ho2 * 128 + wo2) * C_DIM;
            #pragma unroll
            for (int nt = 0; nt < 12; ++nt) {
                const int col = nt*16 + l15;
                x1[base + col] = acc2[nt][rg] + pb[nt] + x[base + col];
            }
        }
    }
}

// ---------------------------------------------------------------------------
// Kernel 2: fused LN2 + MFMA fc1 + GELU + MFMA fc2 + residual, in-place on
// d_out. Hidden chunked by 96 (one LDS h-tile); weights staged transposed.
// grid 2048, block 256. LDS 53248 B -> 3 blocks/CU.  (unchanged)
// ---------------------------------------------------------------------------
__global__ __launch_bounds__(256) void k_mlp(
    const float* x1, const float* __restrict__ g2v, const float* __restrict__ b2v,
    const float* __restrict__ fc1w, const float* __restrict__ fc1b,
    const float* __restrict__ fc2w, const float* __restrict__ fc2b,
    float* out)
{
    __shared__ __align__(16) u16 xn[64 * 192];    // LN2'd tokens bf16, stride 192
    __shared__ __align__(16) u16 wT[192 * 40];    // shared: w1T[96][72] / w2T[192][40]
    __shared__ __align__(16) u16 hbuf[64 * 104];  // GELU'd hidden chunk, stride 104

    const int blk = blockIdx.x;
    const int t = threadIdx.x;
    const size_t row0 = (size_t)blk * 64;
    const int lane = t & 63, w = t >> 6;
    const int l15 = lane & 15, quad = lane >> 4;
    const f32x4 zf = {0.f, 0.f, 0.f, 0.f};

    {   // LN2 staging
        const int nn = t >> 2, q4 = t & 3;
        const float* xp = x1 + (row0 + nn) * C_DIM + q4 * 48;
        float f[48];
        float sum = 0.f, sq = 0.f;
        #pragma unroll
        for (int i = 0; i < 12; ++i) {
            float4 v = *(const float4*)(xp + i * 4);
            f[i*4+0]=v.x; f[i*4+1]=v.y; f[i*4+2]=v.z; f[i*4+3]=v.w;
            sum += v.x+v.y+v.z+v.w;
            sq  += v.x*v.x + v.y*v.y + v.z*v.z + v.w*v.w;
        }
        sum += __shfl_xor(sum,1); sum += __shfl_xor(sum,2);
        sq  += __shfl_xor(sq,1);  sq  += __shfl_xor(sq,2);
        const float mu = sum * (1.f/192.f);
        const float rstd = rsqrtf(sq * (1.f/192.f) - mu*mu + 1e-5f);
        u16* xrow = xn + nn * 192 + q4 * 48;
        #pragma unroll
        for (int i = 0; i < 6; ++i) {
            u32 pk[4];
            #pragma unroll
            for (int j = 0; j < 4; ++j) {
                float g0 = g2v[q4*48 + i*8 + j*2],     b0 = b2v[q4*48 + i*8 + j*2];
                float g1 = g2v[q4*48 + i*8 + j*2 + 1], b1 = b2v[q4*48 + i*8 + j*2 + 1];
                float y0 = (f[i*8+j*2]   - mu) * rstd * g0 + b0;
                float y1 = (f[i*8+j*2+1] - mu) * rstd * g1 + b1;
                pk[j] = (u32)f2bf(y0) | (((u32)f2bf(y1)) << 16);
            }
            *(int4*)(xrow + i*8) = make_int4((int)pk[0], (int)pk[1], (int)pk[2], (int)pk[3]);
        }
    }
    __syncthreads();

    FragU afrag[6];
    #pragma unroll
    for (int kk = 0; kk < 6; ++kk)
        afrag[kk].i4 = *(const int4*)(xn + (w*16 + l15) * 192 + kk*32 + quad*8);

    f32x4 acc2[12];
    #pragma unroll
    for (int nt = 0; nt < 12; ++nt) acc2[nt] = zf;

    for (int hc = 0; hc < 8; ++hc) {
        // ---- fc1 for hidden cols [hc*96, +96) ----
        f32x4 acc1[6];
        #pragma unroll
        for (int nt = 0; nt < 6; ++nt) acc1[nt] = zf;

        for (int kc = 0; kc < 3; ++kc) {
            __syncthreads();
            if (t < 192) {
                const int cc = t % 96, kh = t / 96;
                const float* gp = fc1w + (size_t)(kc*64 + kh*32) * HID_DIM + hc*96 + cc;
                u16* dst = wT + cc*72 + kh*32;
                #pragma unroll
                for (int g = 0; g < 4; ++g) {
                    u32 pk[4];
                    #pragma unroll
                    for (int j2 = 0; j2 < 4; ++j2) {
                        float v0 = gp[(size_t)(g*8 + j2*2    ) * HID_DIM];
                        float v1 = gp[(size_t)(g*8 + j2*2 + 1) * HID_DIM];
                        pk[j2] = (u32)f2bf(v0) | (((u32)f2bf(v1)) << 16);
                    }
                    *(int4*)(dst + g*8) = make_int4((int)pk[0], (int)pk[1], (int)pk[2], (int)pk[3]);
                }
            }
            __syncthreads();
            #pragma unroll
            for (int s = 0; s < 2; ++s) {
                #pragma unroll
                for (int nt = 0; nt < 6; ++nt) {
                    FragU bf_;
                    bf_.i4 = *(const int4*)(wT + (nt*16 + l15)*72 + s*32 + quad*8);
                    acc1[nt] = MFMA_B16(afrag[kc*2 + s].h8, bf_.h8, acc1[nt]);
                }
            }
        }
        // ---- bias + exact GELU -> hbuf (bf16) ----
        #pragma unroll
        for (int nt = 0; nt < 6; ++nt) {
            const float bb = fc1b[hc*96 + nt*16 + l15];
            #pragma unroll
            for (int rg = 0; rg < 4; ++rg) {
                float h = acc1[nt][rg] + bb;
                float g = 0.5f * h * (1.f + erff(h * 0.70710678118654752f));
                hbuf[(w*16 + quad*4 + rg) * 104 + nt*16 + l15] = f2bf(g);
            }
        }
        // ---- fc2 partial over this hidden chunk (3 sub-chunks of 32) ----
        for (int sc = 0; sc < 3; ++sc) {
            __syncthreads();   // hbuf visible; wT reuse safe
            if (t < 192) {
                const float* gp = fc2w + (size_t)(hc*96 + sc*32) * C_DIM + t;
                u16* dst = wT + t*40;
                #pragma unroll
                for (int g = 0; g < 4; ++g) {
                    u32 pk[4];
                    #pragma unroll
                    for (int j2 = 0; j2 < 4; ++j2) {
                        float v0 = gp[(size_t)(g*8 + j2*2    ) * C_DIM];
                        float v1 = gp[(size_t)(g*8 + j2*2 + 1) * C_DIM];
                        pk[j2] = (u32)f2bf(v0) | (((u32)f2bf(v1)) << 16);
                    }
                    *(int4*)(dst + g*8) = make_int4((int)pk[0], (int)pk[1], (int)pk[2], (int)pk[3]);
                }
            }
            __syncthreads();
            FragU ha;
            ha.i4 = *(const int4*)(hbuf + (w*16 + l15) * 104 + sc*32 + quad*8);
            #pragma unroll
            for (int nt = 0; nt < 12; ++nt) {
                FragU bf_;
                bf_.i4 = *(const int4*)(wT + (nt*16 + l15)*40 + quad*8);
                acc2[nt] = MFMA_B16(ha.h8, bf_.h8, acc2[nt]);
            }
        }
    }

    // ---- epilogue: + fc2 bias + residual (in-place safe: 1 owner per cell) ----
    #pragma unroll
    for (int nt = 0; nt < 12; ++nt) {
        const int col = nt*16 + l15;
        const float bb = fc2b[col];
        #pragma unroll
        for (int rg = 0; rg < 4; ++rg) {
            const size_t idx = (row0 + w*16 + quad*4 + rg) * C_DIM + col;
            out[idx] = acc2[nt][rg] + bb + x1[idx];
        }
    }
}

extern "C" void kernel_launch(void* const* d_in, const int* in_sizes, int n_in,
                              void* d_out, int out_size, void* d_ws, size_t ws_size,
                              hipStream_t stream) {
    const float* x     = (const float*)d_in[0];
    // d_in[1]=h, d_in[2]=w (ints, fixed 128 -> hardcoded)
    const float* g1v   = (const float*)d_in[3];
    const float* b1v   = (const float*)d_in[4];
    const float* qkvw  = (const float*)d_in[5];
    const float* qkvb  = (const float*)d_in[6];
    const float* projw = (const float*)d_in[7];
    const float* projb = (const float*)d_in[8];
    const float* relb  = (const float*)d_in[9];
    const float* g2v   = (const float*)d_in[10];
    const float* b2v   = (const float*)d_in[11];
    const float* fc1w  = (const float*)d_in[12];
    const float* fc1b  = (const float*)d_in[13];
    const float* fc2w  = (const float*)d_in[14];
    const float* fc2b  = (const float*)d_in[15];

    float* x1 = (float*)d_out;   // residual stream after attention (f32, token order)

    hipLaunchKernelGGL(k_attnproj, dim3(2048), dim3(256), 0, stream,
                       x, g1v, b1v, qkvw, qkvb, relb, projw, projb, x1);
    hipLaunchKernelGGL(k_mlp, dim3(2048), dim3(256), 0, stream,
                       x1, g2v, b2v, fc1w, fc1b, fc2w, fc2b, x1);  // in-place
}

// Round 3
// 630.701 us; speedup vs baseline: 3.6895x; 1.2157x over previous
//
#include <hip/hip_runtime.h>

typedef unsigned short u16;
typedef unsigned int   u32;
typedef __attribute__((ext_vector_type(8))) short bf16x8;
typedef __attribute__((ext_vector_type(4))) float f32x4;

#define L_TOK   16384
#define C_DIM   192
#define HID_DIM 768

// bf16 weight workspace layout (u16 offsets)
#define OFF_QKV  0          // qkvwT[head][cc=grp*32+dim][k]   6*96*192   = 110592
#define OFF_PROJ 110592     // projT [head][c][j]              6*192*32   =  36864
#define OFF_FC1  147456     // fc1wT [h][k]                    768*192    = 147456
#define OFF_FC2  294912     // fc2wT [c][h]                    192*768    = 147456
#define CVT_TOT  442368     // total u16 elements (884736 B)

union FragU { int4 i4; bf16x8 h8; };

#define MFMA_B16(a,b,c) __builtin_amdgcn_mfma_f32_16x16x32_bf16(a,b,c,0,0,0)

__device__ __forceinline__ u16 f2bf(float f) {
    u32 t; __builtin_memcpy(&t, &f, 4);
    t += 0x7FFFu + ((t >> 16) & 1u);
    return (u16)(t >> 16);
}

// ---------------------------------------------------------------------------
// Kernel 0: one-time f32 -> bf16 weight convert + transpose into workspace.
// Layouts are chosen so every LDS staging tile in k_attnproj / k_mlp is a
// contiguous bf16 row segment (int4-load friendly). ~885 KB, trivial cost.
// ---------------------------------------------------------------------------
__global__ __launch_bounds__(256) void k_cvt(
    const float* __restrict__ qkvw, const float* __restrict__ projw,
    const float* __restrict__ fc1w, const float* __restrict__ fc2w,
    u16* __restrict__ ws)
{
    const int i = blockIdx.x * 256 + threadIdx.x;
    if (i >= CVT_TOT) return;
    float v;
    if (i < OFF_PROJ) {                      // qkvwT[head][cc][k]
        const int k = i % 192, tmp = i / 192;
        const int cc = tmp % 96, head = tmp / 96;
        const int grp = cc >> 5, dim = cc & 31;
        v = qkvw[(size_t)k * 576 + grp * 192 + head * 32 + dim];
    } else if (i < OFF_FC1) {                // projT[head][c][j]
        const int idx = i - OFF_PROJ;
        const int j = idx & 31, tmp = idx >> 5;
        const int c = tmp % 192, head = tmp / 192;
        v = projw[(size_t)(head * 32 + j) * 192 + c];
    } else if (i < OFF_FC2) {                // fc1wT[h][k]
        const int idx = i - OFF_FC1;
        const int k = idx % 192, h = idx / 192;
        v = fc1w[(size_t)k * 768 + h];
    } else {                                 // fc2wT[c][h]
        const int idx = i - OFF_FC2;
        const int h = idx % 768, c = idx / 768;
        v = fc2w[(size_t)h * 192 + c];
    }
    ws[i] = f2bf(v);
}

// ---------------------------------------------------------------------------
// Kernel 1: per-window fused LN1 + MFMA qkv + MFMA scores + softmax + MFMA P@V
// + MFMA proj + residual -> x1 (f32, token order, in d_out).
// grid 2048, block 256 (4 waves; wave w owns query rows w*16..+15).
// Weight staging now reads pre-converted bf16 (contiguous rows): 3 int4
// loads + 3 ds_write_b128 per thread per stage.
// ---------------------------------------------------------------------------
__global__ __launch_bounds__(256) void k_attnproj(
    const float* __restrict__ x, const float* __restrict__ g1v, const float* __restrict__ b1v,
    const u16* __restrict__ qkvwT, const float* __restrict__ qkvb,
    const float* __restrict__ relb, const u16* __restrict__ projT, const float* __restrict__ projb,
    float* __restrict__ x1)
{
    union SmemU {
        u16 xw[64 * 192];                       // 24576 B (phase A only)
        struct {
            u16 qsb[64 * 40];                   //  5120 B  Q rows  [tok][dim]
            u16 ksb[64 * 40];                   //  5120 B  K rows  [tok][dim]
            u16 vsbT[32 * 72];                  //  4608 B  V^T     [dim][tok]
            u16 psb[64 * 72];                   //  9216 B  P       [tok][key]
            u16 oh [64 * 40];                   //  5120 B  O       [tok][dim]
        } s;
    };
    __shared__ __align__(16) SmemU u;
    __shared__ __align__(16) u16 wbuf[192 * 40];   // 15360 B: wTh[96][72] / wP[192][40]
    __shared__ float relbs[225 * 6];               //  5400 B

    const int wi = blockIdx.x;
    const int b  = wi >> 8;
    const int hb = (wi >> 4) & 15;
    const int wb = wi & 15;
    const int t  = threadIdx.x;
    const int lane = t & 63, w = t >> 6;
    const int l15 = lane & 15, quad = lane >> 4;
    const bool maskon = (hb == 15) || (wb == 15);
    const f32x4 zf = {0.f, 0.f, 0.f, 0.f};

    for (int i = t; i < 225 * 6; i += 256) relbs[i] = relb[i];

    // ---- Phase A: load + LayerNorm1, stage to LDS as bf16 ----
    {
        const int n  = t >> 2;
        const int q4 = t & 3;
        const int r = n >> 3, c = n & 7;
        const int ho = (hb * 8 + r + 4) & 127;
        const int wo = (wb * 8 + c + 4) & 127;
        const size_t xoff = ((size_t)b * L_TOK + ho * 128 + wo) * C_DIM;
        const float* xp = x + xoff + q4 * 48;
        float f[48];
        float sum = 0.f, sq = 0.f;
        #pragma unroll
        for (int i = 0; i < 12; ++i) {
            float4 v = *(const float4*)(xp + i * 4);
            f[i*4+0]=v.x; f[i*4+1]=v.y; f[i*4+2]=v.z; f[i*4+3]=v.w;
            sum += v.x+v.y+v.z+v.w;
            sq  += v.x*v.x + v.y*v.y + v.z*v.z + v.w*v.w;
        }
        sum += __shfl_xor(sum, 1); sum += __shfl_xor(sum, 2);
        sq  += __shfl_xor(sq, 1);  sq  += __shfl_xor(sq, 2);
        const float mu = sum * (1.f / 192.f);
        const float rstd = rsqrtf(sq * (1.f / 192.f) - mu * mu + 1e-5f);
        u16* xrow = u.xw + n * 192 + q4 * 48;
        #pragma unroll
        for (int i = 0; i < 6; ++i) {
            u32 pk[4];
            #pragma unroll
            for (int j = 0; j < 4; ++j) {
                float g0 = g1v[q4*48 + i*8 + j*2],     b0 = b1v[q4*48 + i*8 + j*2];
                float g1 = g1v[q4*48 + i*8 + j*2 + 1], b1 = b1v[q4*48 + i*8 + j*2 + 1];
                float y0 = (f[i*8+j*2]   - mu) * rstd * g0 + b0;
                float y1 = (f[i*8+j*2+1] - mu) * rstd * g1 + b1;
                pk[j] = (u32)f2bf(y0) | (((u32)f2bf(y1)) << 16);
            }
            *(int4*)(xrow + i * 8) = make_int4((int)pk[0], (int)pk[1], (int)pk[2], (int)pk[3]);
        }
    }
    __syncthreads();

    FragU afrag[6];
    #pragma unroll
    for (int kk = 0; kk < 6; ++kk)
        afrag[kk].i4 = *(const int4*)(u.xw + (w*16 + l15) * 192 + kk*32 + quad*8);

    const int qrow0 = w*16 + quad*4;

    f32x4 acc2[12];
    #pragma unroll
    for (int nt = 0; nt < 12; ++nt) acc2[nt] = zf;

    for (int head = 0; head < 6; ++head) {
        // ---- Phase B: qkv via MFMA (N=96: q|k|v 32 each), K chunked by 64 ----
        f32x4 accq[6];
        #pragma unroll
        for (int nt = 0; nt < 6; ++nt) accq[nt] = zf;

        for (int kc = 0; kc < 3; ++kc) {
            __syncthreads();   // protects wbuf reuse
            {   // stage 96 cols x 64 k of bf16 weights: 768 int4, 3/thread
                const u16* src = qkvwT + (size_t)head * (96 * 192) + kc * 64;
                #pragma unroll
                for (int i = 0; i < 3; ++i) {
                    const int e = t + i * 256;       // 0..767
                    const int cc = e >> 3, seg = e & 7;
                    *(int4*)(wbuf + cc*72 + seg*8) =
                        *(const int4*)(src + cc*192 + seg*8);
                }
            }
            __syncthreads();
            #pragma unroll
            for (int s = 0; s < 2; ++s) {
                #pragma unroll
                for (int nt = 0; nt < 6; ++nt) {
                    FragU bf_;
                    bf_.i4 = *(const int4*)(wbuf + (nt*16 + l15)*72 + s*32 + quad*8);
                    accq[nt] = MFMA_B16(afrag[kc*2 + s].h8, bf_.h8, accq[nt]);
                }
            }
        }
        // store q/k row-major, v transposed
        #pragma unroll
        for (int nt = 0; nt < 6; ++nt) {
            const int grp = nt >> 1;
            const int dim = (nt & 1)*16 + l15;
            const float bias = qkvb[grp*192 + head*32 + dim];
            float vv[4];
            #pragma unroll
            for (int rg = 0; rg < 4; ++rg) vv[rg] = accq[nt][rg] + bias;
            if (grp == 0) {
                #pragma unroll
                for (int rg = 0; rg < 4; ++rg)
                    u.s.qsb[(qrow0 + rg)*40 + dim] = f2bf(vv[rg] * 0.17677669529663687f);
            } else if (grp == 1) {
                #pragma unroll
                for (int rg = 0; rg < 4; ++rg)
                    u.s.ksb[(qrow0 + rg)*40 + dim] = f2bf(vv[rg]);
            } else {
                u32 lo = (u32)f2bf(vv[0]) | (((u32)f2bf(vv[1])) << 16);
                u32 hi = (u32)f2bf(vv[2]) | (((u32)f2bf(vv[3])) << 16);
                *(uint2*)&u.s.vsbT[dim*72 + w*16 + quad*4] = make_uint2(lo, hi);
            }
        }
        __syncthreads();

        // ---- Phase C: scores via MFMA ----
        FragU qf; qf.i4 = *(const int4*)(u.s.qsb + (w*16 + l15)*40 + quad*8);
        f32x4 sv[4];
        #pragma unroll
        for (int nt = 0; nt < 4; ++nt) {
            FragU kf; kf.i4 = *(const int4*)(u.s.ksb + (nt*16 + l15)*40 + quad*8);
            sv[nt] = MFMA_B16(qf.h8, kf.h8, zf);
        }
        const int kr_ = l15 >> 3, kc2 = l15 & 7;
        #pragma unroll
        for (int rg = 0; rg < 4; ++rg) {
            const int qm = qrow0 + rg;
            const int qr = qm >> 3, qc = qm & 7;
            #pragma unroll
            for (int nt = 0; nt < 4; ++nt) {
                const int kr = nt*2 + kr_;
                sv[nt][rg] += relbs[((qr - kr + 7)*15 + (qc - kc2 + 7))*6 + head];
            }
        }
        if (maskon) {
            #pragma unroll
            for (int rg = 0; rg < 4; ++rg) {
                const int qm = qrow0 + rg;
                const int qr = qm >> 3, qc = qm & 7;
                const int regq = ((hb == 15) ? (qr < 4 ? 1 : 2) : 0) * 3
                               + ((wb == 15) ? (qc < 4 ? 1 : 2) : 0);
                #pragma unroll
                for (int nt = 0; nt < 4; ++nt) {
                    const int kr = nt*2 + kr_;
                    const int regk = ((hb == 15) ? (kr < 4 ? 1 : 2) : 0) * 3
                                   + ((wb == 15) ? (kc2 < 4 ? 1 : 2) : 0);
                    if (regq != regk) sv[nt][rg] -= 100.f;
                }
            }
        }
        // ---- Phase D: softmax ----
        #pragma unroll
        for (int rg = 0; rg < 4; ++rg) {
            float mx = fmaxf(fmaxf(sv[0][rg], sv[1][rg]), fmaxf(sv[2][rg], sv[3][rg]));
            mx = fmaxf(mx, __shfl_xor(mx, 1));
            mx = fmaxf(mx, __shfl_xor(mx, 2));
            mx = fmaxf(mx, __shfl_xor(mx, 4));
            mx = fmaxf(mx, __shfl_xor(mx, 8));
            float s0 = 0.f;
            #pragma unroll
            for (int nt = 0; nt < 4; ++nt) { sv[nt][rg] = __expf(sv[nt][rg] - mx); s0 += sv[nt][rg]; }
            s0 += __shfl_xor(s0, 1); s0 += __shfl_xor(s0, 2);
            s0 += __shfl_xor(s0, 4); s0 += __shfl_xor(s0, 8);
            const float inv = 1.f / s0;
            #pragma unroll
            for (int nt = 0; nt < 4; ++nt)
                u.s.psb[(qrow0 + rg)*72 + nt*16 + l15] = f2bf(sv[nt][rg] * inv);
        }
        // wave-private psb rows -> no barrier

        // ---- Phase E: P@V via MFMA ----
        FragU pa0, pa1;
        pa0.i4 = *(const int4*)(u.s.psb + (w*16 + l15)*72 + quad*8);
        pa1.i4 = *(const int4*)(u.s.psb + (w*16 + l15)*72 + 32 + quad*8);
        f32x4 ov[2];
        ov[0] = zf; ov[1] = zf;
        #pragma unroll
        for (int ntv = 0; ntv < 2; ++ntv) {
            FragU vb0, vb1;
            vb0.i4 = *(const int4*)(u.s.vsbT + (ntv*16 + l15)*72 + quad*8);
            vb1.i4 = *(const int4*)(u.s.vsbT + (ntv*16 + l15)*72 + 32 + quad*8);
            ov[ntv] = MFMA_B16(pa0.h8, vb0.h8, ov[ntv]);
            ov[ntv] = MFMA_B16(pa1.h8, vb1.h8, ov[ntv]);
        }
        #pragma unroll
        for (int ntv = 0; ntv < 2; ++ntv)
            #pragma unroll
            for (int rg = 0; rg < 4; ++rg)
                u.s.oh[(qrow0 + rg)*40 + ntv*16 + l15] = f2bf(ov[ntv][rg]);
        // wave-private oh rows -> no barrier

        // ---- Phase P: stage projT chunk (bf16 rows), proj via MFMA ----
        {
            const u16* src = projT + (size_t)head * (192 * 32);
            #pragma unroll
            for (int i = 0; i < 3; ++i) {
                const int e = t + i * 256;          // 0..767
                const int c = e >> 2, seg = e & 3;
                *(int4*)(wbuf + c*40 + seg*8) =
                    *(const int4*)(src + c*32 + seg*8);
            }
        }
        __syncthreads();
        FragU ao; ao.i4 = *(const int4*)(u.s.oh + (w*16 + l15)*40 + quad*8);
        #pragma unroll
        for (int nt = 0; nt < 12; ++nt) {
            FragU bp; bp.i4 = *(const int4*)(wbuf + (nt*16 + l15)*40 + quad*8);
            acc2[nt] = MFMA_B16(ao.h8, bp.h8, acc2[nt]);
        }
    }

    // ---- Phase F: + proj bias + residual, write x1 ----
    {
        float pb[12];
        #pragma unroll
        for (int nt = 0; nt < 12; ++nt) pb[nt] = projb[nt*16 + l15];
        #pragma unroll
        for (int rg = 0; rg < 4; ++rg) {
            const int tok = qrow0 + rg;
            const int tr = tok >> 3, tc = tok & 7;
            const int ho2 = (hb * 8 + tr + 4) & 127;
            const int wo2 = (wb * 8 + tc + 4) & 127;
            const size_t base = ((size_t)b * L_TOK + ho2 * 128 + wo2) * C_DIM;
            #pragma unroll
            for (int nt = 0; nt < 12; ++nt) {
                const int col = nt*16 + l15;
                x1[base + col] = acc2[nt][rg] + pb[nt] + x[base + col];
            }
        }
    }
}

// ---------------------------------------------------------------------------
// Kernel 2: fused LN2 + MFMA fc1 + GELU + MFMA fc2 + residual, in-place.
// Weight staging from pre-converted bf16 transposed layouts.
// grid 2048, block 256. LDS 53248 B -> 3 blocks/CU.
// ---------------------------------------------------------------------------
__global__ __launch_bounds__(256) void k_mlp(
    const float* x1, const float* __restrict__ g2v, const float* __restrict__ b2v,
    const u16* __restrict__ fc1wT, const float* __restrict__ fc1b,
    const u16* __restrict__ fc2wT, const float* __restrict__ fc2b,
    float* out)
{
    __shared__ __align__(16) u16 xn[64 * 192];
    __shared__ __align__(16) u16 wT[192 * 40];
    __shared__ __align__(16) u16 hbuf[64 * 104];

    const int blk = blockIdx.x;
    const int t = threadIdx.x;
    const size_t row0 = (size_t)blk * 64;
    const int lane = t & 63, w = t >> 6;
    const int l15 = lane & 15, quad = lane >> 4;
    const f32x4 zf = {0.f, 0.f, 0.f, 0.f};

    {   // LN2 staging
        const int nn = t >> 2, q4 = t & 3;
        const float* xp = x1 + (row0 + nn) * C_DIM + q4 * 48;
        float f[48];
        float sum = 0.f, sq = 0.f;
        #pragma unroll
        for (int i = 0; i < 12; ++i) {
            float4 v = *(const float4*)(xp + i * 4);
            f[i*4+0]=v.x; f[i*4+1]=v.y; f[i*4+2]=v.z; f[i*4+3]=v.w;
            sum += v.x+v.y+v.z+v.w;
            sq  += v.x*v.x + v.y*v.y + v.z*v.z + v.w*v.w;
        }
        sum += __shfl_xor(sum,1); sum += __shfl_xor(sum,2);
        sq  += __shfl_xor(sq,1);  sq  += __shfl_xor(sq,2);
        const float mu = sum * (1.f/192.f);
        const float rstd = rsqrtf(sq * (1.f/192.f) - mu*mu + 1e-5f);
        u16* xrow = xn + nn * 192 + q4 * 48;
        #pragma unroll
        for (int i = 0; i < 6; ++i) {
            u32 pk[4];
            #pragma unroll
            for (int j = 0; j < 4; ++j) {
                float g0 = g2v[q4*48 + i*8 + j*2],     b0 = b2v[q4*48 + i*8 + j*2];
                float g1 = g2v[q4*48 + i*8 + j*2 + 1], b1 = b2v[q4*48 + i*8 + j*2 + 1];
                float y0 = (f[i*8+j*2]   - mu) * rstd * g0 + b0;
                float y1 = (f[i*8+j*2+1] - mu) * rstd * g1 + b1;
                pk[j] = (u32)f2bf(y0) | (((u32)f2bf(y1)) << 16);
            }
            *(int4*)(xrow + i*8) = make_int4((int)pk[0], (int)pk[1], (int)pk[2], (int)pk[3]);
        }
    }
    __syncthreads();

    FragU afrag[6];
    #pragma unroll
    for (int kk = 0; kk < 6; ++kk)
        afrag[kk].i4 = *(const int4*)(xn + (w*16 + l15) * 192 + kk*32 + quad*8);

    f32x4 acc2[12];
    #pragma unroll
    for (int nt = 0; nt < 12; ++nt) acc2[nt] = zf;

    for (int hc = 0; hc < 8; ++hc) {
        // ---- fc1 for hidden cols [hc*96, +96) ----
        f32x4 acc1[6];
        #pragma unroll
        for (int nt = 0; nt < 6; ++nt) acc1[nt] = zf;

        for (int kc = 0; kc < 3; ++kc) {
            __syncthreads();
            {   // stage fc1wT rows: 96 cols x 64 k, 768 int4, 3/thread
                const u16* src = fc1wT + (size_t)(hc * 96) * 192 + kc * 64;
                #pragma unroll
                for (int i = 0; i < 3; ++i) {
                    const int e = t + i * 256;
                    const int cc = e >> 3, seg = e & 7;
                    *(int4*)(wT + cc*72 + seg*8) =
                        *(const int4*)(src + cc*192 + seg*8);
                }
            }
            __syncthreads();
            #pragma unroll
            for (int s = 0; s < 2; ++s) {
                #pragma unroll
                for (int nt = 0; nt < 6; ++nt) {
                    FragU bf_;
                    bf_.i4 = *(const int4*)(wT + (nt*16 + l15)*72 + s*32 + quad*8);
                    acc1[nt] = MFMA_B16(afrag[kc*2 + s].h8, bf_.h8, acc1[nt]);
                }
            }
        }
        // ---- bias + exact GELU -> hbuf (bf16) ----
        #pragma unroll
        for (int nt = 0; nt < 6; ++nt) {
            const float bb = fc1b[hc*96 + nt*16 + l15];
            #pragma unroll
            for (int rg = 0; rg < 4; ++rg) {
                float h = acc1[nt][rg] + bb;
                float g = 0.5f * h * (1.f + erff(h * 0.70710678118654752f));
                hbuf[(w*16 + quad*4 + rg) * 104 + nt*16 + l15] = f2bf(g);
            }
        }
        // ---- fc2 partial over this hidden chunk (3 sub-chunks of 32) ----
        for (int sc = 0; sc < 3; ++sc) {
            __syncthreads();
            {   // stage fc2wT: 192 cols x 32 h, 768 int4, 3/thread
                const u16* src = fc2wT + hc * 96 + sc * 32;
                #pragma unroll
                for (int i = 0; i < 3; ++i) {
                    const int e = t + i * 256;
                    const int c = e >> 2, seg = e & 3;
                    *(int4*)(wT + c*40 + seg*8) =
                        *(const int4*)(src + c*768 + seg*8);
                }
            }
            __syncthreads();
            FragU ha;
            ha.i4 = *(const int4*)(hbuf + (w*16 + l15) * 104 + sc*32 + quad*8);
            #pragma unroll
            for (int nt = 0; nt < 12; ++nt) {
                FragU bf_;
                bf_.i4 = *(const int4*)(wT + (nt*16 + l15)*40 + quad*8);
                acc2[nt] = MFMA_B16(ha.h8, bf_.h8, acc2[nt]);
            }
        }
    }

    // ---- epilogue: + fc2 bias + residual ----
    #pragma unroll
    for (int nt = 0; nt < 12; ++nt) {
        const int col = nt*16 + l15;
        const float bb = fc2b[col];
        #pragma unroll
        for (int rg = 0; rg < 4; ++rg) {
            const size_t idx = (row0 + w*16 + quad*4 + rg) * C_DIM + col;
            out[idx] = acc2[nt][rg] + bb + x1[idx];
        }
    }
}

extern "C" void kernel_launch(void* const* d_in, const int* in_sizes, int n_in,
                              void* d_out, int out_size, void* d_ws, size_t ws_size,
                              hipStream_t stream) {
    const float* x     = (const float*)d_in[0];
    // d_in[1]=h, d_in[2]=w (ints, fixed 128 -> hardcoded)
    const float* g1v   = (const float*)d_in[3];
    const float* b1v   = (const float*)d_in[4];
    const float* qkvw  = (const float*)d_in[5];
    const float* qkvb  = (const float*)d_in[6];
    const float* projw = (const float*)d_in[7];
    const float* projb = (const float*)d_in[8];
    const float* relb  = (const float*)d_in[9];
    const float* g2v   = (const float*)d_in[10];
    const float* b2v   = (const float*)d_in[11];
    const float* fc1w  = (const float*)d_in[12];
    const float* fc1b  = (const float*)d_in[13];
    const float* fc2w  = (const float*)d_in[14];
    const float* fc2b  = (const float*)d_in[15];

    float* x1 = (float*)d_out;
    u16* wsb  = (u16*)d_ws;      // 884736 B of bf16 weights

    hipLaunchKernelGGL(k_cvt, dim3((CVT_TOT + 255) / 256), dim3(256), 0, stream,
                       qkvw, projw, fc1w, fc2w, wsb);
    hipLaunchKernelGGL(k_attnproj, dim3(2048), dim3(256), 0, stream,
                       x, g1v, b1v, wsb + OFF_QKV, qkvb, relb, wsb + OFF_PROJ, projb, x1);
    hipLaunchKernelGGL(k_mlp, dim3(2048), dim3(256), 0, stream,
                       x1, g2v, b2v, wsb + OFF_FC1, fc1b, wsb + OFF_FC2, fc2b, x1);
}

// Round 4
// 601.490 us; speedup vs baseline: 3.8687x; 1.0486x over previous
//
#include <hip/hip_runtime.h>

typedef unsigned short u16;
typedef unsigned int   u32;
typedef __attribute__((ext_vector_type(8))) short bf16x8;
typedef __attribute__((ext_vector_type(4))) float f32x4;

#define L_TOK   16384
#define C_DIM   192
#define HID_DIM 768

// bf16 weight workspace layout (u16 offsets)
#define OFF_QKV  0          // qkvwT[head][cc=grp*32+dim][k]   6*96*192   = 110592
#define OFF_PROJ 110592     // projT [head][c][j]              6*192*32   =  36864
#define OFF_FC1  147456     // fc1wT [h][k]                    768*192    = 147456
#define OFF_FC2  294912     // fc2wT [c][h]                    192*768    = 147456
#define CVT_TOT  442368     // total u16 elements (884736 B)

union FragU { int4 i4; bf16x8 h8; };

#define MFMA_B16(a,b,c) __builtin_amdgcn_mfma_f32_16x16x32_bf16(a,b,c,0,0,0)

__device__ __forceinline__ u16 f2bf(float f) {
    u32 t; __builtin_memcpy(&t, &f, 4);
    t += 0x7FFFu + ((t >> 16) & 1u);
    return (u16)(t >> 16);
}

// ---------------------------------------------------------------------------
// Kernel 0: one-time f32 -> bf16 weight convert + transpose into workspace.
// ---------------------------------------------------------------------------
__global__ __launch_bounds__(256) void k_cvt(
    const float* __restrict__ qkvw, const float* __restrict__ projw,
    const float* __restrict__ fc1w, const float* __restrict__ fc2w,
    u16* __restrict__ ws)
{
    const int i = blockIdx.x * 256 + threadIdx.x;
    if (i >= CVT_TOT) return;
    float v;
    if (i < OFF_PROJ) {                      // qkvwT[head][cc][k]
        const int k = i % 192, tmp = i / 192;
        const int cc = tmp % 96, head = tmp / 96;
        const int grp = cc >> 5, dim = cc & 31;
        v = qkvw[(size_t)k * 576 + grp * 192 + head * 32 + dim];
    } else if (i < OFF_FC1) {                // projT[head][c][j]
        const int idx = i - OFF_PROJ;
        const int j = idx & 31, tmp = idx >> 5;
        const int c = tmp % 192, head = tmp / 192;
        v = projw[(size_t)(head * 32 + j) * 192 + c];
    } else if (i < OFF_FC2) {                // fc1wT[h][k]
        const int idx = i - OFF_FC1;
        const int k = idx % 192, h = idx / 192;
        v = fc1w[(size_t)k * 768 + h];
    } else {                                 // fc2wT[c][h]
        const int idx = i - OFF_FC2;
        const int h = idx % 768, c = idx / 768;
        v = fc2w[(size_t)h * 192 + c];
    }
    ws[i] = f2bf(v);
}

// ---------------------------------------------------------------------------
// Kernel 1: per-window fused LN1 + MFMA qkv + MFMA scores + softmax + MFMA P@V
// + MFMA proj + residual -> x1. grid 2048, block 256.
// xw stride padded 192->200 u16 (100 words = 4 mod 32: afrag preload was a
// 16-way bank conflict at stride 96 words, now 2-way/free).
// ---------------------------------------------------------------------------
__global__ __launch_bounds__(256) void k_attnproj(
    const float* __restrict__ x, const float* __restrict__ g1v, const float* __restrict__ b1v,
    const u16* __restrict__ qkvwT, const float* __restrict__ qkvb,
    const float* __restrict__ relb, const u16* __restrict__ projT, const float* __restrict__ projb,
    float* __restrict__ x1)
{
    union SmemU {
        u16 xw[64 * 200];                       // 25600 B (phase A only, padded)
        struct {
            u16 qsb[64 * 40];                   //  5120 B  Q rows  [tok][dim]
            u16 ksb[64 * 40];                   //  5120 B  K rows  [tok][dim]
            u16 vsbT[32 * 72];                  //  4608 B  V^T     [dim][tok]
            u16 psb[64 * 72];                   //  9216 B  P       [tok][key]
            u16 oh [64 * 40];                   //  5120 B  O       [tok][dim]
        } s;
    };
    __shared__ __align__(16) SmemU u;
    __shared__ __align__(16) u16 wbuf[192 * 40];   // 15360 B: wTh[96][72] / wP[192][40]
    __shared__ float relbs[225 * 6];               //  5400 B

    const int wi = blockIdx.x;
    const int b  = wi >> 8;
    const int hb = (wi >> 4) & 15;
    const int wb = wi & 15;
    const int t  = threadIdx.x;
    const int lane = t & 63, w = t >> 6;
    const int l15 = lane & 15, quad = lane >> 4;
    const bool maskon = (hb == 15) || (wb == 15);
    const f32x4 zf = {0.f, 0.f, 0.f, 0.f};

    for (int i = t; i < 225 * 6; i += 256) relbs[i] = relb[i];

    // ---- Phase A: load + LayerNorm1, stage to LDS as bf16 ----
    {
        const int n  = t >> 2;
        const int q4 = t & 3;
        const int r = n >> 3, c = n & 7;
        const int ho = (hb * 8 + r + 4) & 127;
        const int wo = (wb * 8 + c + 4) & 127;
        const size_t xoff = ((size_t)b * L_TOK + ho * 128 + wo) * C_DIM;
        const float* xp = x + xoff + q4 * 48;
        float f[48];
        float sum = 0.f, sq = 0.f;
        #pragma unroll
        for (int i = 0; i < 12; ++i) {
            float4 v = *(const float4*)(xp + i * 4);
            f[i*4+0]=v.x; f[i*4+1]=v.y; f[i*4+2]=v.z; f[i*4+3]=v.w;
            sum += v.x+v.y+v.z+v.w;
            sq  += v.x*v.x + v.y*v.y + v.z*v.z + v.w*v.w;
        }
        sum += __shfl_xor(sum, 1); sum += __shfl_xor(sum, 2);
        sq  += __shfl_xor(sq, 1);  sq  += __shfl_xor(sq, 2);
        const float mu = sum * (1.f / 192.f);
        const float rstd = rsqrtf(sq * (1.f / 192.f) - mu * mu + 1e-5f);
        u16* xrow = u.xw + n * 200 + q4 * 48;
        #pragma unroll
        for (int i = 0; i < 6; ++i) {
            u32 pk[4];
            #pragma unroll
            for (int j = 0; j < 4; ++j) {
                float g0 = g1v[q4*48 + i*8 + j*2],     b0 = b1v[q4*48 + i*8 + j*2];
                float g1 = g1v[q4*48 + i*8 + j*2 + 1], b1 = b1v[q4*48 + i*8 + j*2 + 1];
                float y0 = (f[i*8+j*2]   - mu) * rstd * g0 + b0;
                float y1 = (f[i*8+j*2+1] - mu) * rstd * g1 + b1;
                pk[j] = (u32)f2bf(y0) | (((u32)f2bf(y1)) << 16);
            }
            *(int4*)(xrow + i * 8) = make_int4((int)pk[0], (int)pk[1], (int)pk[2], (int)pk[3]);
        }
    }
    __syncthreads();

    FragU afrag[6];
    #pragma unroll
    for (int kk = 0; kk < 6; ++kk)
        afrag[kk].i4 = *(const int4*)(u.xw + (w*16 + l15) * 200 + kk*32 + quad*8);

    const int qrow0 = w*16 + quad*4;

    f32x4 acc2[12];
    #pragma unroll
    for (int nt = 0; nt < 12; ++nt) acc2[nt] = zf;

    for (int head = 0; head < 6; ++head) {
        // ---- Phase B: qkv via MFMA ----
        f32x4 accq[6];
        #pragma unroll
        for (int nt = 0; nt < 6; ++nt) accq[nt] = zf;

        for (int kc = 0; kc < 3; ++kc) {
            __syncthreads();
            {   // stage 96 cols x 64 k of bf16 weights: 768 int4, 3/thread
                const u16* src = qkvwT + (size_t)head * (96 * 192) + kc * 64;
                #pragma unroll
                for (int i = 0; i < 3; ++i) {
                    const int e = t + i * 256;
                    const int cc = e >> 3, seg = e & 7;
                    *(int4*)(wbuf + cc*72 + seg*8) =
                        *(const int4*)(src + cc*192 + seg*8);
                }
            }
            __syncthreads();
            #pragma unroll
            for (int s = 0; s < 2; ++s) {
                #pragma unroll
                for (int nt = 0; nt < 6; ++nt) {
                    FragU bf_;
                    bf_.i4 = *(const int4*)(wbuf + (nt*16 + l15)*72 + s*32 + quad*8);
                    accq[nt] = MFMA_B16(afrag[kc*2 + s].h8, bf_.h8, accq[nt]);
                }
            }
        }
        // store q/k row-major, v transposed
        #pragma unroll
        for (int nt = 0; nt < 6; ++nt) {
            const int grp = nt >> 1;
            const int dim = (nt & 1)*16 + l15;
            const float bias = qkvb[grp*192 + head*32 + dim];
            float vv[4];
            #pragma unroll
            for (int rg = 0; rg < 4; ++rg) vv[rg] = accq[nt][rg] + bias;
            if (grp == 0) {
                #pragma unroll
                for (int rg = 0; rg < 4; ++rg)
                    u.s.qsb[(qrow0 + rg)*40 + dim] = f2bf(vv[rg] * 0.17677669529663687f);
            } else if (grp == 1) {
                #pragma unroll
                for (int rg = 0; rg < 4; ++rg)
                    u.s.ksb[(qrow0 + rg)*40 + dim] = f2bf(vv[rg]);
            } else {
                u32 lo = (u32)f2bf(vv[0]) | (((u32)f2bf(vv[1])) << 16);
                u32 hi = (u32)f2bf(vv[2]) | (((u32)f2bf(vv[3])) << 16);
                *(uint2*)&u.s.vsbT[dim*72 + w*16 + quad*4] = make_uint2(lo, hi);
            }
        }
        __syncthreads();

        // ---- Phase C: scores via MFMA ----
        FragU qf; qf.i4 = *(const int4*)(u.s.qsb + (w*16 + l15)*40 + quad*8);
        f32x4 sv[4];
        #pragma unroll
        for (int nt = 0; nt < 4; ++nt) {
            FragU kf; kf.i4 = *(const int4*)(u.s.ksb + (nt*16 + l15)*40 + quad*8);
            sv[nt] = MFMA_B16(qf.h8, kf.h8, zf);
        }
        const int kr_ = l15 >> 3, kc2 = l15 & 7;
        #pragma unroll
        for (int rg = 0; rg < 4; ++rg) {
            const int qm = qrow0 + rg;
            const int qr = qm >> 3, qc = qm & 7;
            #pragma unroll
            for (int nt = 0; nt < 4; ++nt) {
                const int kr = nt*2 + kr_;
                sv[nt][rg] += relbs[((qr - kr + 7)*15 + (qc - kc2 + 7))*6 + head];
            }
        }
        if (maskon) {
            #pragma unroll
            for (int rg = 0; rg < 4; ++rg) {
                const int qm = qrow0 + rg;
                const int qr = qm >> 3, qc = qm & 7;
                const int regq = ((hb == 15) ? (qr < 4 ? 1 : 2) : 0) * 3
                               + ((wb == 15) ? (qc < 4 ? 1 : 2) : 0);
                #pragma unroll
                for (int nt = 0; nt < 4; ++nt) {
                    const int kr = nt*2 + kr_;
                    const int regk = ((hb == 15) ? (kr < 4 ? 1 : 2) : 0) * 3
                                   + ((wb == 15) ? (kc2 < 4 ? 1 : 2) : 0);
                    if (regq != regk) sv[nt][rg] -= 100.f;
                }
            }
        }
        // ---- Phase D: softmax ----
        #pragma unroll
        for (int rg = 0; rg < 4; ++rg) {
            float mx = fmaxf(fmaxf(sv[0][rg], sv[1][rg]), fmaxf(sv[2][rg], sv[3][rg]));
            mx = fmaxf(mx, __shfl_xor(mx, 1));
            mx = fmaxf(mx, __shfl_xor(mx, 2));
            mx = fmaxf(mx, __shfl_xor(mx, 4));
            mx = fmaxf(mx, __shfl_xor(mx, 8));
            float s0 = 0.f;
            #pragma unroll
            for (int nt = 0; nt < 4; ++nt) { sv[nt][rg] = __expf(sv[nt][rg] - mx); s0 += sv[nt][rg]; }
            s0 += __shfl_xor(s0, 1); s0 += __shfl_xor(s0, 2);
            s0 += __shfl_xor(s0, 4); s0 += __shfl_xor(s0, 8);
            const float inv = 1.f / s0;
            #pragma unroll
            for (int nt = 0; nt < 4; ++nt)
                u.s.psb[(qrow0 + rg)*72 + nt*16 + l15] = f2bf(sv[nt][rg] * inv);
        }

        // ---- Phase E: P@V via MFMA ----
        FragU pa0, pa1;
        pa0.i4 = *(const int4*)(u.s.psb + (w*16 + l15)*72 + quad*8);
        pa1.i4 = *(const int4*)(u.s.psb + (w*16 + l15)*72 + 32 + quad*8);
        f32x4 ov[2];
        ov[0] = zf; ov[1] = zf;
        #pragma unroll
        for (int ntv = 0; ntv < 2; ++ntv) {
            FragU vb0, vb1;
            vb0.i4 = *(const int4*)(u.s.vsbT + (ntv*16 + l15)*72 + quad*8);
            vb1.i4 = *(const int4*)(u.s.vsbT + (ntv*16 + l15)*72 + 32 + quad*8);
            ov[ntv] = MFMA_B16(pa0.h8, vb0.h8, ov[ntv]);
            ov[ntv] = MFMA_B16(pa1.h8, vb1.h8, ov[ntv]);
        }
        #pragma unroll
        for (int ntv = 0; ntv < 2; ++ntv)
            #pragma unroll
            for (int rg = 0; rg < 4; ++rg)
                u.s.oh[(qrow0 + rg)*40 + ntv*16 + l15] = f2bf(ov[ntv][rg]);

        // ---- Phase P: stage projT chunk, proj via MFMA ----
        {
            const u16* src = projT + (size_t)head * (192 * 32);
            #pragma unroll
            for (int i = 0; i < 3; ++i) {
                const int e = t + i * 256;
                const int c = e >> 2, seg = e & 3;
                *(int4*)(wbuf + c*40 + seg*8) =
                    *(const int4*)(src + c*32 + seg*8);
            }
        }
        __syncthreads();
        FragU ao; ao.i4 = *(const int4*)(u.s.oh + (w*16 + l15)*40 + quad*8);
        #pragma unroll
        for (int nt = 0; nt < 12; ++nt) {
            FragU bp; bp.i4 = *(const int4*)(wbuf + (nt*16 + l15)*40 + quad*8);
            acc2[nt] = MFMA_B16(ao.h8, bp.h8, acc2[nt]);
        }
    }

    // ---- Phase F: + proj bias + residual, write x1 ----
    {
        float pb[12];
        #pragma unroll
        for (int nt = 0; nt < 12; ++nt) pb[nt] = projb[nt*16 + l15];
        #pragma unroll
        for (int rg = 0; rg < 4; ++rg) {
            const int tok = qrow0 + rg;
            const int tr = tok >> 3, tc = tok & 7;
            const int ho2 = (hb * 8 + tr + 4) & 127;
            const int wo2 = (wb * 8 + tc + 4) & 127;
            const size_t base = ((size_t)b * L_TOK + ho2 * 128 + wo2) * C_DIM;
            #pragma unroll
            for (int nt = 0; nt < 12; ++nt) {
                const int col = nt*16 + l15;
                x1[base + col] = acc2[nt][rg] + pb[nt] + x[base + col];
            }
        }
    }
}

// ---------------------------------------------------------------------------
// Kernel 2 v2: 128 tokens/block (grid 1024, block 256; each wave owns TWO
// 16-row M-tiles). Per-token weight staging + barrier count halved; each
// staged B-fragment feeds 2 MFMAs. LDS: union{xn[128][200], hbuf[128][104]}
// 51.2KB + wT 15.4KB = 66.6KB -> 2 blocks/CU.
// ---------------------------------------------------------------------------
__global__ __launch_bounds__(256, 2) void k_mlp(
    const float* x1, const float* __restrict__ g2v, const float* __restrict__ b2v,
    const u16* __restrict__ fc1wT, const float* __restrict__ fc1b,
    const u16* __restrict__ fc2wT, const float* __restrict__ fc2b,
    float* out)
{
    union SmemU {
        u16 xn[128 * 200];     // 51200 B  LN2'd tokens (stride-padded)
        u16 hbuf[128 * 104];   // 26624 B  GELU'd hidden chunk (xn dead by then)
    };
    __shared__ __align__(16) SmemU u;
    __shared__ __align__(16) u16 wT[192 * 40];   // 15360 B: w1T[96][72] / w2T[192][40]

    const int blk = blockIdx.x;
    const int t = threadIdx.x;
    const size_t row0 = (size_t)blk * 128;
    const int lane = t & 63, w = t >> 6;
    const int l15 = lane & 15, quad = lane >> 4;
    const f32x4 zf = {0.f, 0.f, 0.f, 0.f};

    // ---- LN2 staging: 128 tokens, 2 per quartet-thread ----
    #pragma unroll
    for (int tk = 0; tk < 2; ++tk) {
        const int nn = t >> 2, q4 = t & 3;
        const int tok = tk * 64 + nn;
        const float* xp = x1 + (row0 + tok) * C_DIM + q4 * 48;
        float f[48];
        float sum = 0.f, sq = 0.f;
        #pragma unroll
        for (int i = 0; i < 12; ++i) {
            float4 v = *(const float4*)(xp + i * 4);
            f[i*4+0]=v.x; f[i*4+1]=v.y; f[i*4+2]=v.z; f[i*4+3]=v.w;
            sum += v.x+v.y+v.z+v.w;
            sq  += v.x*v.x + v.y*v.y + v.z*v.z + v.w*v.w;
        }
        sum += __shfl_xor(sum,1); sum += __shfl_xor(sum,2);
        sq  += __shfl_xor(sq,1);  sq  += __shfl_xor(sq,2);
        const float mu = sum * (1.f/192.f);
        const float rstd = rsqrtf(sq * (1.f/192.f) - mu*mu + 1e-5f);
        u16* xrow = u.xn + tok * 200 + q4 * 48;
        #pragma unroll
        for (int i = 0; i < 6; ++i) {
            u32 pk[4];
            #pragma unroll
            for (int j = 0; j < 4; ++j) {
                float g0 = g2v[q4*48 + i*8 + j*2],     b0 = b2v[q4*48 + i*8 + j*2];
                float g1 = g2v[q4*48 + i*8 + j*2 + 1], b1 = b2v[q4*48 + i*8 + j*2 + 1];
                float y0 = (f[i*8+j*2]   - mu) * rstd * g0 + b0;
                float y1 = (f[i*8+j*2+1] - mu) * rstd * g1 + b1;
                pk[j] = (u32)f2bf(y0) | (((u32)f2bf(y1)) << 16);
            }
            *(int4*)(xrow + i*8) = make_int4((int)pk[0], (int)pk[1], (int)pk[2], (int)pk[3]);
        }
    }
    __syncthreads();

    // A-fragments for both M-tiles (mt: token = mt*64 + w*16 + l15)
    FragU afrag[2][6];
    #pragma unroll
    for (int mt = 0; mt < 2; ++mt)
        #pragma unroll
        for (int kk = 0; kk < 6; ++kk)
            afrag[mt][kk].i4 = *(const int4*)(u.xn + (mt*64 + w*16 + l15) * 200 + kk*32 + quad*8);
    // xn dead after this point (all waves pass >=2 barriers before hbuf write)

    f32x4 acc2[2][12];
    #pragma unroll
    for (int mt = 0; mt < 2; ++mt)
        #pragma unroll
        for (int nt = 0; nt < 12; ++nt) acc2[mt][nt] = zf;

    for (int hc = 0; hc < 8; ++hc) {
        // ---- fc1 for hidden cols [hc*96, +96) ----
        f32x4 acc1[2][6];
        #pragma unroll
        for (int mt = 0; mt < 2; ++mt)
            #pragma unroll
            for (int nt = 0; nt < 6; ++nt) acc1[mt][nt] = zf;

        for (int kc = 0; kc < 3; ++kc) {
            __syncthreads();
            {   // stage fc1wT rows: 96 cols x 64 k, 768 int4, 3/thread
                const u16* src = fc1wT + (size_t)(hc * 96) * 192 + kc * 64;
                #pragma unroll
                for (int i = 0; i < 3; ++i) {
                    const int e = t + i * 256;
                    const int cc = e >> 3, seg = e & 7;
                    *(int4*)(wT + cc*72 + seg*8) =
                        *(const int4*)(src + cc*192 + seg*8);
                }
            }
            __syncthreads();
            #pragma unroll
            for (int s = 0; s < 2; ++s) {
                #pragma unroll
                for (int nt = 0; nt < 6; ++nt) {
                    FragU bf_;
                    bf_.i4 = *(const int4*)(wT + (nt*16 + l15)*72 + s*32 + quad*8);
                    acc1[0][nt] = MFMA_B16(afrag[0][kc*2 + s].h8, bf_.h8, acc1[0][nt]);
                    acc1[1][nt] = MFMA_B16(afrag[1][kc*2 + s].h8, bf_.h8, acc1[1][nt]);
                }
            }
        }
        // ---- bias + exact GELU -> hbuf (bf16), both M-tiles ----
        #pragma unroll
        for (int nt = 0; nt < 6; ++nt) {
            const float bb = fc1b[hc*96 + nt*16 + l15];
            #pragma unroll
            for (int mt = 0; mt < 2; ++mt) {
                #pragma unroll
                for (int rg = 0; rg < 4; ++rg) {
                    float h = acc1[mt][nt][rg] + bb;
                    float g = 0.5f * h * (1.f + erff(h * 0.70710678118654752f));
                    u.hbuf[(mt*64 + w*16 + quad*4 + rg) * 104 + nt*16 + l15] = f2bf(g);
                }
            }
        }
        // ---- fc2 partial over this hidden chunk (3 sub-chunks of 32) ----
        for (int sc = 0; sc < 3; ++sc) {
            __syncthreads();
            {   // stage fc2wT: 192 cols x 32 h, 768 int4, 3/thread
                const u16* src = fc2wT + hc * 96 + sc * 32;
                #pragma unroll
                for (int i = 0; i < 3; ++i) {
                    const int e = t + i * 256;
                    const int c = e >> 2, seg = e & 3;
                    *(int4*)(wT + c*40 + seg*8) =
                        *(const int4*)(src + c*768 + seg*8);
                }
            }
            __syncthreads();
            FragU ha0, ha1;
            ha0.i4 = *(const int4*)(u.hbuf + (w*16 + l15) * 104 + sc*32 + quad*8);
            ha1.i4 = *(const int4*)(u.hbuf + (64 + w*16 + l15) * 104 + sc*32 + quad*8);
            #pragma unroll
            for (int nt = 0; nt < 12; ++nt) {
                FragU bf_;
                bf_.i4 = *(const int4*)(wT + (nt*16 + l15)*40 + quad*8);
                acc2[0][nt] = MFMA_B16(ha0.h8, bf_.h8, acc2[0][nt]);
                acc2[1][nt] = MFMA_B16(ha1.h8, bf_.h8, acc2[1][nt]);
            }
        }
    }

    // ---- epilogue: + fc2 bias + residual (in-place safe) ----
    #pragma unroll
    for (int nt = 0; nt < 12; ++nt) {
        const int col = nt*16 + l15;
        const float bb = fc2b[col];
        #pragma unroll
        for (int mt = 0; mt < 2; ++mt) {
            #pragma unroll
            for (int rg = 0; rg < 4; ++rg) {
                const size_t idx = (row0 + mt*64 + w*16 + quad*4 + rg) * C_DIM + col;
                out[idx] = acc2[mt][nt][rg] + bb + x1[idx];
            }
        }
    }
}

extern "C" void kernel_launch(void* const* d_in, const int* in_sizes, int n_in,
                              void* d_out, int out_size, void* d_ws, size_t ws_size,
                              hipStream_t stream) {
    const float* x     = (const float*)d_in[0];
    // d_in[1]=h, d_in[2]=w (ints, fixed 128 -> hardcoded)
    const float* g1v   = (const float*)d_in[3];
    const float* b1v   = (const float*)d_in[4];
    const float* qkvw  = (const float*)d_in[5];
    const float* qkvb  = (const float*)d_in[6];
    const float* projw = (const float*)d_in[7];
    const float* projb = (const float*)d_in[8];
    const float* relb  = (const float*)d_in[9];
    const float* g2v   = (const float*)d_in[10];
    const float* b2v   = (const float*)d_in[11];
    const float* fc1w  = (const float*)d_in[12];
    const float* fc1b  = (const float*)d_in[13];
    const float* fc2w  = (const float*)d_in[14];
    const float* fc2b  = (const float*)d_in[15];

    float* x1 = (float*)d_out;
    u16* wsb  = (u16*)d_ws;      // 884736 B of bf16 weights

    hipLaunchKernelGGL(k_cvt, dim3((CVT_TOT + 255) / 256), dim3(256), 0, stream,
                       qkvw, projw, fc1w, fc2w, wsb);
    hipLaunchKernelGGL(k_attnproj, dim3(2048), dim3(256), 0, stream,
                       x, g1v, b1v, wsb + OFF_QKV, qkvb, relb, wsb + OFF_PROJ, projb, x1);
    hipLaunchKernelGGL(k_mlp, dim3(1024), dim3(256), 0, stream,
                       x1, g2v, b2v, wsb + OFF_FC1, fc1b, wsb + OFF_FC2, fc2b, x1);
}

// Round 5
// 557.794 us; speedup vs baseline: 4.1718x; 1.0783x over previous
//
#include <hip/hip_runtime.h>

typedef unsigned short u16;
typedef unsigned int   u32;
typedef __attribute__((ext_vector_type(8))) short bf16x8;
typedef __attribute__((ext_vector_type(4))) float f32x4;

#define L_TOK   16384
#define C_DIM   192
#define HID_DIM 768

// bf16 weight workspace layout (u16 offsets)
#define OFF_QKV  0          // qkvwT[head][cc=grp*32+dim][k]   6*96*192   = 110592
#define OFF_PROJ 110592     // projT [head][c][j]              6*192*32   =  36864
#define OFF_FC1  147456     // fc1wT [h][k]                    768*192    = 147456
#define OFF_FC2  294912     // fc2wT [c][h]                    192*768    = 147456
#define CVT_TOT  442368     // total u16 elements (884736 B)

union FragU { int4 i4; bf16x8 h8; };

#define MFMA_B16(a,b,c) __builtin_amdgcn_mfma_f32_16x16x32_bf16(a,b,c,0,0,0)

__device__ __forceinline__ u16 f2bf(float f) {
    u32 t; __builtin_memcpy(&t, &f, 4);
    t += 0x7FFFu + ((t >> 16) & 1u);
    return (u16)(t >> 16);
}

// ---------------------------------------------------------------------------
// Kernel 0: one-time f32 -> bf16 weight convert + transpose into workspace.
// ---------------------------------------------------------------------------
__global__ __launch_bounds__(256) void k_cvt(
    const float* __restrict__ qkvw, const float* __restrict__ projw,
    const float* __restrict__ fc1w, const float* __restrict__ fc2w,
    u16* __restrict__ ws)
{
    const int i = blockIdx.x * 256 + threadIdx.x;
    if (i >= CVT_TOT) return;
    float v;
    if (i < OFF_PROJ) {                      // qkvwT[head][cc][k]
        const int k = i % 192, tmp = i / 192;
        const int cc = tmp % 96, head = tmp / 96;
        const int grp = cc >> 5, dim = cc & 31;
        v = qkvw[(size_t)k * 576 + grp * 192 + head * 32 + dim];
    } else if (i < OFF_FC1) {                // projT[head][c][j]
        const int idx = i - OFF_PROJ;
        const int j = idx & 31, tmp = idx >> 5;
        const int c = tmp % 192, head = tmp / 192;
        v = projw[(size_t)(head * 32 + j) * 192 + c];
    } else if (i < OFF_FC2) {                // fc1wT[h][k]
        const int idx = i - OFF_FC1;
        const int k = idx % 192, h = idx / 192;
        v = fc1w[(size_t)k * 768 + h];
    } else {                                 // fc2wT[c][h]
        const int idx = i - OFF_FC2;
        const int h = idx % 768, c = idx / 768;
        v = fc2w[(size_t)h * 192 + c];
    }
    ws[i] = f2bf(v);
}

// ---------------------------------------------------------------------------
// Kernel 1 v3: TWO windows per block (grid 1024, block 256, 4 waves).
// Waves 0-1 own window A (32 query rows each), waves 2-3 window B.
// qkv/proj weight stages are shared by both windows -> per-token staging
// traffic and barrier count halved; 24 MFMAs per stage phase (was 12).
// LDS: union{xw[128][200], pw[2]} 58.4KB + wbuf 15.4KB + relbs 5.4KB
// = 79.1KB -> 2 blocks/CU (8 waves/CU).
// ---------------------------------------------------------------------------
__global__ __launch_bounds__(256, 2) void k_attnproj(
    const float* __restrict__ x, const float* __restrict__ g1v, const float* __restrict__ b1v,
    const u16* __restrict__ qkvwT, const float* __restrict__ qkvb,
    const float* __restrict__ relb, const u16* __restrict__ projT, const float* __restrict__ projb,
    float* __restrict__ x1)
{
    struct PW {
        u16 qsb[64 * 40];                   //  5120 B  Q rows  [tok][dim]
        u16 ksb[64 * 40];                   //  5120 B  K rows  [tok][dim]
        u16 vsbT[32 * 72];                  //  4608 B  V^T     [dim][tok]
        u16 psb[64 * 72];                   //  9216 B  P       [tok][key]
        u16 oh [64 * 40];                   //  5120 B  O       [tok][dim]
    };                                      // 29184 B per window
    union SmemU {
        u16 xw[128 * 200];                  // 51200 B (phase A only, padded stride)
        PW pw[2];                           // 58368 B
    };
    __shared__ __align__(16) SmemU u;
    __shared__ __align__(16) u16 wbuf[192 * 40];   // 15360 B: wTh[96][72] / wP[192][40]
    __shared__ float relbs[225 * 6];               //  5400 B

    const int t  = threadIdx.x;
    const int lane = t & 63, w = t >> 6;
    const int win = w >> 1, half = w & 1;   // wave's window + row-half
    const int l15 = lane & 15, quad = lane >> 4;
    const int wi2 = blockIdx.x * 2 + win;   // this wave's window index
    const int b  = wi2 >> 8;
    const int hb = (wi2 >> 4) & 15;
    const int wb = wi2 & 15;
    const bool maskon = (hb == 15) || (wb == 15);
    const f32x4 zf = {0.f, 0.f, 0.f, 0.f};

    for (int i = t; i < 225 * 6; i += 256) relbs[i] = relb[i];

    // ---- Phase A: LN1 for 128 tokens (both windows), 2 per quartet-thread ----
    #pragma unroll
    for (int tk = 0; tk < 2; ++tk) {
        const int nn = t >> 2, q4 = t & 3;
        const int tok = tk * 64 + nn;       // 0..127
        const int tw = tok >> 6, n = tok & 63;
        const int wiA = blockIdx.x * 2 + tw;
        const int bA  = wiA >> 8;
        const int hbA = (wiA >> 4) & 15, wbA = wiA & 15;
        const int r = n >> 3, c = n & 7;
        const int ho = (hbA * 8 + r + 4) & 127;   // undo roll(-4,-4)
        const int wo = (wbA * 8 + c + 4) & 127;
        const size_t xoff = ((size_t)bA * L_TOK + ho * 128 + wo) * C_DIM;
        const float* xp = x + xoff + q4 * 48;
        float f[48];
        float sum = 0.f, sq = 0.f;
        #pragma unroll
        for (int i = 0; i < 12; ++i) {
            float4 v = *(const float4*)(xp + i * 4);
            f[i*4+0]=v.x; f[i*4+1]=v.y; f[i*4+2]=v.z; f[i*4+3]=v.w;
            sum += v.x+v.y+v.z+v.w;
            sq  += v.x*v.x + v.y*v.y + v.z*v.z + v.w*v.w;
        }
        sum += __shfl_xor(sum, 1); sum += __shfl_xor(sum, 2);
        sq  += __shfl_xor(sq, 1);  sq  += __shfl_xor(sq, 2);
        const float mu = sum * (1.f / 192.f);
        const float rstd = rsqrtf(sq * (1.f / 192.f) - mu * mu + 1e-5f);
        u16* xrow = u.xw + tok * 200 + q4 * 48;
        #pragma unroll
        for (int i = 0; i < 6; ++i) {
            u32 pk[4];
            #pragma unroll
            for (int j = 0; j < 4; ++j) {
                float g0 = g1v[q4*48 + i*8 + j*2],     b0 = b1v[q4*48 + i*8 + j*2];
                float g1 = g1v[q4*48 + i*8 + j*2 + 1], b1 = b1v[q4*48 + i*8 + j*2 + 1];
                float y0 = (f[i*8+j*2]   - mu) * rstd * g0 + b0;
                float y1 = (f[i*8+j*2+1] - mu) * rstd * g1 + b1;
                pk[j] = (u32)f2bf(y0) | (((u32)f2bf(y1)) << 16);
            }
            *(int4*)(xrow + i * 8) = make_int4((int)pk[0], (int)pk[1], (int)pk[2], (int)pk[3]);
        }
    }
    __syncthreads();

    // A-fragments: this wave's 2 M-tiles (window-local rows half*32 + mt*16 + l15)
    FragU afrag[2][6];
    #pragma unroll
    for (int mt = 0; mt < 2; ++mt)
        #pragma unroll
        for (int kk = 0; kk < 6; ++kk)
            afrag[mt][kk].i4 = *(const int4*)(u.xw +
                (win*64 + half*32 + mt*16 + l15) * 200 + kk*32 + quad*8);
    // xw dead from here (first pw write happens after >=3 barriers below).

    PW* P = &u.pw[win];
    const int rb = half*32 + quad*4;        // window-local row base (add mt*16)

    f32x4 acc2[2][12];
    #pragma unroll
    for (int mt = 0; mt < 2; ++mt)
        #pragma unroll
        for (int nt = 0; nt < 12; ++nt) acc2[mt][nt] = zf;

    for (int head = 0; head < 6; ++head) {
        // ---- Phase B: qkv via MFMA, weights staged once for both windows ----
        f32x4 accq[2][6];
        #pragma unroll
        for (int mt = 0; mt < 2; ++mt)
            #pragma unroll
            for (int nt = 0; nt < 6; ++nt) accq[mt][nt] = zf;

        for (int kc = 0; kc < 3; ++kc) {
            __syncthreads();   // protects wbuf reuse
            {   // stage 96 cols x 64 k of bf16 weights: 768 int4, 3/thread
                const u16* src = qkvwT + (size_t)head * (96 * 192) + kc * 64;
                #pragma unroll
                for (int i = 0; i < 3; ++i) {
                    const int e = t + i * 256;
                    const int cc = e >> 3, seg = e & 7;
                    *(int4*)(wbuf + cc*72 + seg*8) =
                        *(const int4*)(src + cc*192 + seg*8);
                }
            }
            __syncthreads();
            #pragma unroll
            for (int s = 0; s < 2; ++s) {
                #pragma unroll
                for (int nt = 0; nt < 6; ++nt) {
                    FragU bf_;
                    bf_.i4 = *(const int4*)(wbuf + (nt*16 + l15)*72 + s*32 + quad*8);
                    accq[0][nt] = MFMA_B16(afrag[0][kc*2 + s].h8, bf_.h8, accq[0][nt]);
                    accq[1][nt] = MFMA_B16(afrag[1][kc*2 + s].h8, bf_.h8, accq[1][nt]);
                }
            }
        }
        // store q/k row-major, v transposed (into this wave's window buffers)
        #pragma unroll
        for (int mt = 0; mt < 2; ++mt) {
            #pragma unroll
            for (int nt = 0; nt < 6; ++nt) {
                const int grp = nt >> 1;
                const int dim = (nt & 1)*16 + l15;
                const float bias = qkvb[grp*192 + head*32 + dim];
                float vv[4];
                #pragma unroll
                for (int rg = 0; rg < 4; ++rg) vv[rg] = accq[mt][nt][rg] + bias;
                const int rowb = rb + mt*16;
                if (grp == 0) {
                    #pragma unroll
                    for (int rg = 0; rg < 4; ++rg)
                        P->qsb[(rowb + rg)*40 + dim] = f2bf(vv[rg] * 0.17677669529663687f);
                } else if (grp == 1) {
                    #pragma unroll
                    for (int rg = 0; rg < 4; ++rg)
                        P->ksb[(rowb + rg)*40 + dim] = f2bf(vv[rg]);
                } else {
                    u32 lo = (u32)f2bf(vv[0]) | (((u32)f2bf(vv[1])) << 16);
                    u32 hi = (u32)f2bf(vv[2]) | (((u32)f2bf(vv[3])) << 16);
                    *(uint2*)&P->vsbT[dim*72 + rowb] = make_uint2(lo, hi);
                }
            }
        }
        __syncthreads();   // window's q/k/vT visible to its 2 waves

        // ---- Phase C: scores via MFMA (2 M-tiles vs all 64 keys) ----
        FragU qf0, qf1;
        qf0.i4 = *(const int4*)(P->qsb + (half*32 + l15)*40 + quad*8);
        qf1.i4 = *(const int4*)(P->qsb + (half*32 + 16 + l15)*40 + quad*8);
        f32x4 sv[2][4];
        #pragma unroll
        for (int nt = 0; nt < 4; ++nt) {
            FragU kf; kf.i4 = *(const int4*)(P->ksb + (nt*16 + l15)*40 + quad*8);
            sv[0][nt] = MFMA_B16(qf0.h8, kf.h8, zf);
            sv[1][nt] = MFMA_B16(qf1.h8, kf.h8, zf);
        }
        const int kr_ = l15 >> 3, kc2 = l15 & 7;
        #pragma unroll
        for (int mt = 0; mt < 2; ++mt) {
            #pragma unroll
            for (int rg = 0; rg < 4; ++rg) {
                const int qm = rb + mt*16 + rg;
                const int qr = qm >> 3, qc = qm & 7;
                #pragma unroll
                for (int nt = 0; nt < 4; ++nt) {
                    const int kr = nt*2 + kr_;
                    sv[mt][nt][rg] += relbs[((qr - kr + 7)*15 + (qc - kc2 + 7))*6 + head];
                }
            }
        }
        if (maskon) {
            #pragma unroll
            for (int mt = 0; mt < 2; ++mt) {
                #pragma unroll
                for (int rg = 0; rg < 4; ++rg) {
                    const int qm = rb + mt*16 + rg;
                    const int qr = qm >> 3, qc = qm & 7;
                    const int regq = ((hb == 15) ? (qr < 4 ? 1 : 2) : 0) * 3
                                   + ((wb == 15) ? (qc < 4 ? 1 : 2) : 0);
                    #pragma unroll
                    for (int nt = 0; nt < 4; ++nt) {
                        const int kr = nt*2 + kr_;
                        const int regk = ((hb == 15) ? (kr < 4 ? 1 : 2) : 0) * 3
                                       + ((wb == 15) ? (kc2 < 4 ? 1 : 2) : 0);
                        if (regq != regk) sv[mt][nt][rg] -= 100.f;
                    }
                }
            }
        }
        // ---- Phase D: softmax (row spread across 16-lane group) ----
        #pragma unroll
        for (int mt = 0; mt < 2; ++mt) {
            #pragma unroll
            for (int rg = 0; rg < 4; ++rg) {
                float mx = fmaxf(fmaxf(sv[mt][0][rg], sv[mt][1][rg]),
                                 fmaxf(sv[mt][2][rg], sv[mt][3][rg]));
                mx = fmaxf(mx, __shfl_xor(mx, 1));
                mx = fmaxf(mx, __shfl_xor(mx, 2));
                mx = fmaxf(mx, __shfl_xor(mx, 4));
                mx = fmaxf(mx, __shfl_xor(mx, 8));
                float s0 = 0.f;
                #pragma unroll
                for (int nt = 0; nt < 4; ++nt) {
                    sv[mt][nt][rg] = __expf(sv[mt][nt][rg] - mx); s0 += sv[mt][nt][rg];
                }
                s0 += __shfl_xor(s0, 1); s0 += __shfl_xor(s0, 2);
                s0 += __shfl_xor(s0, 4); s0 += __shfl_xor(s0, 8);
                const float inv = 1.f / s0;
                #pragma unroll
                for (int nt = 0; nt < 4; ++nt)
                    P->psb[(rb + mt*16 + rg)*72 + nt*16 + l15] = f2bf(sv[mt][nt][rg] * inv);
            }
        }
        // psb/oh rows are wave-private -> no barrier around E.

        // ---- Phase E: P@V via MFMA ----
        FragU vb[2][2];
        #pragma unroll
        for (int ntv = 0; ntv < 2; ++ntv) {
            vb[ntv][0].i4 = *(const int4*)(P->vsbT + (ntv*16 + l15)*72 + quad*8);
            vb[ntv][1].i4 = *(const int4*)(P->vsbT + (ntv*16 + l15)*72 + 32 + quad*8);
        }
        #pragma unroll
        for (int mt = 0; mt < 2; ++mt) {
            FragU pa0, pa1;
            pa0.i4 = *(const int4*)(P->psb + (half*32 + mt*16 + l15)*72 + quad*8);
            pa1.i4 = *(const int4*)(P->psb + (half*32 + mt*16 + l15)*72 + 32 + quad*8);
            f32x4 ov0 = zf, ov1 = zf;
            ov0 = MFMA_B16(pa0.h8, vb[0][0].h8, ov0);
            ov0 = MFMA_B16(pa1.h8, vb[0][1].h8, ov0);
            ov1 = MFMA_B16(pa0.h8, vb[1][0].h8, ov1);
            ov1 = MFMA_B16(pa1.h8, vb[1][1].h8, ov1);
            #pragma unroll
            for (int rg = 0; rg < 4; ++rg) {
                P->oh[(rb + mt*16 + rg)*40 + l15]      = f2bf(ov0[rg]);
                P->oh[(rb + mt*16 + rg)*40 + 16 + l15] = f2bf(ov1[rg]);
            }
        }

        // ---- Phase P: stage projT chunk (shared), proj via MFMA ----
        {   // prior wbuf reads all happened before the post-qkv barrier -> safe
            const u16* src = projT + (size_t)head * (192 * 32);
            #pragma unroll
            for (int i = 0; i < 3; ++i) {
                const int e = t + i * 256;
                const int c = e >> 2, seg = e & 3;
                *(int4*)(wbuf + c*40 + seg*8) =
                    *(const int4*)(src + c*32 + seg*8);
            }
        }
        __syncthreads();
        FragU ao0, ao1;
        ao0.i4 = *(const int4*)(P->oh + (half*32 + l15)*40 + quad*8);
        ao1.i4 = *(const int4*)(P->oh + (half*32 + 16 + l15)*40 + quad*8);
        #pragma unroll
        for (int nt = 0; nt < 12; ++nt) {
            FragU bp; bp.i4 = *(const int4*)(wbuf + (nt*16 + l15)*40 + quad*8);
            acc2[0][nt] = MFMA_B16(ao0.h8, bp.h8, acc2[0][nt]);
            acc2[1][nt] = MFMA_B16(ao1.h8, bp.h8, acc2[1][nt]);
        }
        // next head's kc-loop barrier protects wbuf before restaging
    }

    // ---- Phase F: + proj bias + residual, write x1 ----
    {
        float pb[12];
        #pragma unroll
        for (int nt = 0; nt < 12; ++nt) pb[nt] = projb[nt*16 + l15];
        #pragma unroll
        for (int mt = 0; mt < 2; ++mt) {
            #pragma unroll
            for (int rg = 0; rg < 4; ++rg) {
                const int tok = rb + mt*16 + rg;          // window-local
                const int tr = tok >> 3, tc = tok & 7;
                const int ho2 = (hb * 8 + tr + 4) & 127;
                const int wo2 = (wb * 8 + tc + 4) & 127;
                const size_t base = ((size_t)b * L_TOK + ho2 * 128 + wo2) * C_DIM;
                #pragma unroll
                for (int nt = 0; nt < 12; ++nt) {
                    const int col = nt*16 + l15;
                    x1[base + col] = acc2[mt][nt][rg] + pb[nt] + x[base + col];
                }
            }
        }
    }
}

// ---------------------------------------------------------------------------
// Kernel 2 v2: 128 tokens/block (grid 1024, block 256). Unchanged from R3.
// ---------------------------------------------------------------------------
__global__ __launch_bounds__(256, 2) void k_mlp(
    const float* x1, const float* __restrict__ g2v, const float* __restrict__ b2v,
    const u16* __restrict__ fc1wT, const float* __restrict__ fc1b,
    const u16* __restrict__ fc2wT, const float* __restrict__ fc2b,
    float* out)
{
    union SmemU {
        u16 xn[128 * 200];     // 51200 B  LN2'd tokens (stride-padded)
        u16 hbuf[128 * 104];   // 26624 B  GELU'd hidden chunk (xn dead by then)
    };
    __shared__ __align__(16) SmemU u;
    __shared__ __align__(16) u16 wT[192 * 40];   // 15360 B

    const int blk = blockIdx.x;
    const int t = threadIdx.x;
    const size_t row0 = (size_t)blk * 128;
    const int lane = t & 63, w = t >> 6;
    const int l15 = lane & 15, quad = lane >> 4;
    const f32x4 zf = {0.f, 0.f, 0.f, 0.f};

    #pragma unroll
    for (int tk = 0; tk < 2; ++tk) {
        const int nn = t >> 2, q4 = t & 3;
        const int tok = tk * 64 + nn;
        const float* xp = x1 + (row0 + tok) * C_DIM + q4 * 48;
        float f[48];
        float sum = 0.f, sq = 0.f;
        #pragma unroll
        for (int i = 0; i < 12; ++i) {
            float4 v = *(const float4*)(xp + i * 4);
            f[i*4+0]=v.x; f[i*4+1]=v.y; f[i*4+2]=v.z; f[i*4+3]=v.w;
            sum += v.x+v.y+v.z+v.w;
            sq  += v.x*v.x + v.y*v.y + v.z*v.z + v.w*v.w;
        }
        sum += __shfl_xor(sum,1); sum += __shfl_xor(sum,2);
        sq  += __shfl_xor(sq,1);  sq  += __shfl_xor(sq,2);
        const float mu = sum * (1.f/192.f);
        const float rstd = rsqrtf(sq * (1.f/192.f) - mu*mu + 1e-5f);
        u16* xrow = u.xn + tok * 200 + q4 * 48;
        #pragma unroll
        for (int i = 0; i < 6; ++i) {
            u32 pk[4];
            #pragma unroll
            for (int j = 0; j < 4; ++j) {
                float g0 = g2v[q4*48 + i*8 + j*2],     b0 = b2v[q4*48 + i*8 + j*2];
                float g1 = g2v[q4*48 + i*8 + j*2 + 1], b1 = b2v[q4*48 + i*8 + j*2 + 1];
                float y0 = (f[i*8+j*2]   - mu) * rstd * g0 + b0;
                float y1 = (f[i*8+j*2+1] - mu) * rstd * g1 + b1;
                pk[j] = (u32)f2bf(y0) | (((u32)f2bf(y1)) << 16);
            }
            *(int4*)(xrow + i*8) = make_int4((int)pk[0], (int)pk[1], (int)pk[2], (int)pk[3]);
        }
    }
    __syncthreads();

    FragU afrag[2][6];
    #pragma unroll
    for (int mt = 0; mt < 2; ++mt)
        #pragma unroll
        for (int kk = 0; kk < 6; ++kk)
            afrag[mt][kk].i4 = *(const int4*)(u.xn + (mt*64 + w*16 + l15) * 200 + kk*32 + quad*8);

    f32x4 acc2[2][12];
    #pragma unroll
    for (int mt = 0; mt < 2; ++mt)
        #pragma unroll
        for (int nt = 0; nt < 12; ++nt) acc2[mt][nt] = zf;

    for (int hc = 0; hc < 8; ++hc) {
        f32x4 acc1[2][6];
        #pragma unroll
        for (int mt = 0; mt < 2; ++mt)
            #pragma unroll
            for (int nt = 0; nt < 6; ++nt) acc1[mt][nt] = zf;

        for (int kc = 0; kc < 3; ++kc) {
            __syncthreads();
            {
                const u16* src = fc1wT + (size_t)(hc * 96) * 192 + kc * 64;
                #pragma unroll
                for (int i = 0; i < 3; ++i) {
                    const int e = t + i * 256;
                    const int cc = e >> 3, seg = e & 7;
                    *(int4*)(wT + cc*72 + seg*8) =
                        *(const int4*)(src + cc*192 + seg*8);
                }
            }
            __syncthreads();
            #pragma unroll
            for (int s = 0; s < 2; ++s) {
                #pragma unroll
                for (int nt = 0; nt < 6; ++nt) {
                    FragU bf_;
                    bf_.i4 = *(const int4*)(wT + (nt*16 + l15)*72 + s*32 + quad*8);
                    acc1[0][nt] = MFMA_B16(afrag[0][kc*2 + s].h8, bf_.h8, acc1[0][nt]);
                    acc1[1][nt] = MFMA_B16(afrag[1][kc*2 + s].h8, bf_.h8, acc1[1][nt]);
                }
            }
        }
        #pragma unroll
        for (int nt = 0; nt < 6; ++nt) {
            const float bb = fc1b[hc*96 + nt*16 + l15];
            #pragma unroll
            for (int mt = 0; mt < 2; ++mt) {
                #pragma unroll
                for (int rg = 0; rg < 4; ++rg) {
                    float h = acc1[mt][nt][rg] + bb;
                    float g = 0.5f * h * (1.f + erff(h * 0.70710678118654752f));
                    u.hbuf[(mt*64 + w*16 + quad*4 + rg) * 104 + nt*16 + l15] = f2bf(g);
                }
            }
        }
        for (int sc = 0; sc < 3; ++sc) {
            __syncthreads();
            {
                const u16* src = fc2wT + hc * 96 + sc * 32;
                #pragma unroll
                for (int i = 0; i < 3; ++i) {
                    const int e = t + i * 256;
                    const int c = e >> 2, seg = e & 3;
                    *(int4*)(wT + c*40 + seg*8) =
                        *(const int4*)(src + c*768 + seg*8);
                }
            }
            __syncthreads();
            FragU ha0, ha1;
            ha0.i4 = *(const int4*)(u.hbuf + (w*16 + l15) * 104 + sc*32 + quad*8);
            ha1.i4 = *(const int4*)(u.hbuf + (64 + w*16 + l15) * 104 + sc*32 + quad*8);
            #pragma unroll
            for (int nt = 0; nt < 12; ++nt) {
                FragU bf_;
                bf_.i4 = *(const int4*)(wT + (nt*16 + l15)*40 + quad*8);
                acc2[0][nt] = MFMA_B16(ha0.h8, bf_.h8, acc2[0][nt]);
                acc2[1][nt] = MFMA_B16(ha1.h8, bf_.h8, acc2[1][nt]);
            }
        }
    }

    #pragma unroll
    for (int nt = 0; nt < 12; ++nt) {
        const int col = nt*16 + l15;
        const float bb = fc2b[col];
        #pragma unroll
        for (int mt = 0; mt < 2; ++mt) {
            #pragma unroll
            for (int rg = 0; rg < 4; ++rg) {
                const size_t idx = (row0 + mt*64 + w*16 + quad*4 + rg) * C_DIM + col;
                out[idx] = acc2[mt][nt][rg] + bb + x1[idx];
            }
        }
    }
}

extern "C" void kernel_launch(void* const* d_in, const int* in_sizes, int n_in,
                              void* d_out, int out_size, void* d_ws, size_t ws_size,
                              hipStream_t stream) {
    const float* x     = (const float*)d_in[0];
    // d_in[1]=h, d_in[2]=w (ints, fixed 128 -> hardcoded)
    const float* g1v   = (const float*)d_in[3];
    const float* b1v   = (const float*)d_in[4];
    const float* qkvw  = (const float*)d_in[5];
    const float* qkvb  = (const float*)d_in[6];
    const float* projw = (const float*)d_in[7];
    const float* projb = (const float*)d_in[8];
    const float* relb  = (const float*)d_in[9];
    const float* g2v   = (const float*)d_in[10];
    const float* b2v   = (const float*)d_in[11];
    const float* fc1w  = (const float*)d_in[12];
    const float* fc1b  = (const float*)d_in[13];
    const float* fc2w  = (const float*)d_in[14];
    const float* fc2b  = (const float*)d_in[15];

    float* x1 = (float*)d_out;
    u16* wsb  = (u16*)d_ws;      // 884736 B of bf16 weights

    hipLaunchKernelGGL(k_cvt, dim3((CVT_TOT + 255) / 256), dim3(256), 0, stream,
                       qkvw, projw, fc1w, fc2w, wsb);
    hipLaunchKernelGGL(k_attnproj, dim3(1024), dim3(256), 0, stream,
                       x, g1v, b1v, wsb + OFF_QKV, qkvb, relb, wsb + OFF_PROJ, projb, x1);
    hipLaunchKernelGGL(k_mlp, dim3(1024), dim3(256), 0, stream,
                       x1, g2v, b2v, wsb + OFF_FC1, fc1b, wsb + OFF_FC2, fc2b, x1);
}